// Round 12
// baseline (110.980 us; speedup 1.0000x reference)
//
#include <hip/hip_runtime.h>
#include <stdint.h>

#define T_SEQ 4096
#define NB 2
#define D_MODEL 2048
#define HD 128

typedef __attribute__((ext_vector_type(4)))  float f32x4;
typedef __attribute__((ext_vector_type(16))) float f32x16;
typedef __attribute__((ext_vector_type(8)))  short bf16x8;
typedef __attribute__((ext_vector_type(4)))  unsigned u32x4;

#define LAMBDA_INIT 0.7836057665316244f
#define OUT_SCALE   0.21639423346837556f

__device__ __forceinline__ unsigned short f2bf(float f) {
  unsigned int u = __float_as_uint(f);
  u += 0x7FFFu + ((u >> 16) & 1u);
  return (unsigned short)(u >> 16);
}
__device__ __forceinline__ float bf2f(unsigned short h) {
  return __uint_as_float(((unsigned int)h) << 16);
}
__device__ __forceinline__ unsigned cvt_pk_bf16(float a, float b) {
  unsigned r;
  asm("v_cvt_pk_bf16_f32 %0, %1, %2" : "=v"(r) : "v"(a), "v"(b));
  return r;
}

// ---------------- Kernel 0: pre-pack W into fragment-ordered bf16 ---------
__global__ __launch_bounds__(256) void wtrans(
    const float* __restrict__ wq, const float* __restrict__ wk,
    const float* __restrict__ wv, unsigned short* __restrict__ wT)
{
  const int which = blockIdx.y;
  const int s = blockIdx.x;                     // k-slab 0..31
  const float* w = (which == 0) ? wq : ((which == 1) ? wk : wv);
  const float scale = (which == 0) ? 0.125f : 1.0f;
  const int tid = threadIdx.x;
  #pragma unroll
  for (int j = 0; j < 4; ++j) {
    int cell = j * 256 + tid;                   // 0..1023
    int q = cell >> 7, n = cell & 127;
    int kb = s * 64 + q * 8;
    float v[8];
    #pragma unroll
    for (int e = 0; e < 8; ++e) v[e] = w[(size_t)(kb + e) * HD + n] * scale;
    u32x4 pk = { cvt_pk_bf16(v[0], v[1]), cvt_pk_bf16(v[2], v[3]),
                 cvt_pk_bf16(v[4], v[5]), cvt_pk_bf16(v[6], v[7]) };
    *reinterpret_cast<u32x4*>(&wT[(size_t)(which * 32 + s) * 8192 + (size_t)cell * 8]) = pk;
  }
}

// ---------------- Kernel 1a: QKV K-split partials --------------------------
// 3072 waves: (type 3) x (mt 256) x (nh 2) x (ks 2); M=32 x N=64 x K=1024.
// A prefetch 4 batches deep (x latency ~600-900cy); B 2 deep (L2-hot wT).
// sched_barrier(0) walls pin issue order so the allocator cannot sink loads.
__global__ __launch_bounds__(256, 3) void qkv_part(
    const float* __restrict__ x, const unsigned short* __restrict__ wT,
    float* __restrict__ P)
{
  const int tid = threadIdx.x;
  const int lane = tid & 63, wid = tid >> 6;
  const int wgid = blockIdx.x * 4 + wid;
  const int ks   = wgid & 1;
  const int nh   = (wgid >> 1) & 1;
  const int mt   = (wgid >> 2) & 255;
  const int type = wgid >> 10;
  const int fr = lane & 15, fq = lane >> 4;
  const int m0 = mt * 32;

  const float* xa = x + (size_t)(m0 + fr) * D_MODEL + ks * 1024;
  const float* xb = xa + (size_t)16 * D_MODEL;
  const unsigned short* wbase = wT + (size_t)type * 262144
                              + (size_t)(ks * 16) * 8192
                              + (size_t)(nh * 64 + fr) * 8;

  f32x4 acc0[4], acc1[4];
  #pragma unroll
  for (int j = 0; j < 4; ++j) {
    acc0[j] = (f32x4){0.f, 0.f, 0.f, 0.f};
    acc1[j] = (f32x4){0.f, 0.f, 0.f, 0.f};
  }

  f32x4 X0[4], X1[4], X2[4], X3[4];
  bf16x8 B0[4], B1[4];

#define AISSUE(S, t) do {                                                  \
    const int k0_ = (t) * 32 + fq * 8;                                     \
    S[0] = *reinterpret_cast<const f32x4*>(xa + k0_);                      \
    S[1] = *reinterpret_cast<const f32x4*>(xa + k0_ + 4);                  \
    S[2] = *reinterpret_cast<const f32x4*>(xb + k0_);                      \
    S[3] = *reinterpret_cast<const f32x4*>(xb + k0_ + 4);                  \
  } while (0)

#define BISSUE(Bc, t) do {                                                 \
    const unsigned short* bp_ = wbase + (size_t)((t) >> 1) * 8192          \
                              + (size_t)((((t) & 1) * 4 + fq) * 128) * 8;  \
    _Pragma("unroll")                                                      \
    for (int ni = 0; ni < 4; ++ni)                                         \
      Bc[ni] = *reinterpret_cast<const bf16x8*>(bp_ + (size_t)ni * 128);   \
  } while (0)

#define QITER(S, Bc) do {                                                  \
    u32x4 ua_ = { cvt_pk_bf16(S[0][0], S[0][1]),                           \
                  cvt_pk_bf16(S[0][2], S[0][3]),                           \
                  cvt_pk_bf16(S[1][0], S[1][1]),                           \
                  cvt_pk_bf16(S[1][2], S[1][3]) };                         \
    u32x4 ub_ = { cvt_pk_bf16(S[2][0], S[2][1]),                           \
                  cvt_pk_bf16(S[2][2], S[2][3]),                           \
                  cvt_pk_bf16(S[3][0], S[3][1]),                           \
                  cvt_pk_bf16(S[3][2], S[3][3]) };                         \
    bf16x8 a0_ = *reinterpret_cast<bf16x8*>(&ua_);                         \
    bf16x8 a1_ = *reinterpret_cast<bf16x8*>(&ub_);                         \
    _Pragma("unroll")                                                      \
    for (int ni = 0; ni < 4; ++ni) {                                       \
      acc0[ni] = __builtin_amdgcn_mfma_f32_16x16x32_bf16(a0_, Bc[ni], acc0[ni], 0, 0, 0); \
      acc1[ni] = __builtin_amdgcn_mfma_f32_16x16x32_bf16(a1_, Bc[ni], acc1[ni], 0, 0, 0); \
    }                                                                      \
  } while (0)

  AISSUE(X0, 0); AISSUE(X1, 1); AISSUE(X2, 2); AISSUE(X3, 3);
  BISSUE(B0, 0); BISSUE(B1, 1);
  __builtin_amdgcn_sched_barrier(0);

  #pragma unroll 1
  for (int u = 0; u < 8; ++u) {
    const int t0 = 4 * u;
    QITER(X0, B0);
    if (t0 + 4 < 32) AISSUE(X0, t0 + 4);
    if (t0 + 2 < 32) BISSUE(B0, t0 + 2);
    __builtin_amdgcn_sched_barrier(0);
    QITER(X1, B1);
    if (t0 + 5 < 32) AISSUE(X1, t0 + 5);
    if (t0 + 3 < 32) BISSUE(B1, t0 + 3);
    __builtin_amdgcn_sched_barrier(0);
    QITER(X2, B0);
    if (t0 + 6 < 32) AISSUE(X2, t0 + 6);
    if (t0 + 4 < 32) BISSUE(B0, t0 + 4);
    __builtin_amdgcn_sched_barrier(0);
    QITER(X3, B1);
    if (t0 + 7 < 32) AISSUE(X3, t0 + 7);
    if (t0 + 5 < 32) BISSUE(B1, t0 + 5);
    __builtin_amdgcn_sched_barrier(0);
  }
#undef QITER
#undef BISSUE
#undef AISSUE

  // partial store: P[((ks*3+type)*8192 + m)*128 + n]
  float* pp = P + ((size_t)(ks * 3 + type) * 8192 + m0) * 128 + nh * 64;
  #pragma unroll
  for (int mi = 0; mi < 2; ++mi)
    #pragma unroll
    for (int ni = 0; ni < 4; ++ni)
      #pragma unroll
      for (int r = 0; r < 4; ++r) {
        float vv = mi ? acc1[ni][r] : acc0[ni][r];
        pp[(size_t)(mi * 16 + fq * 4 + r) * 128 + ni * 16 + fr] = vv;
      }
}

// ---------------- Kernel 1b: merge partials + fragment scatter ------------
__global__ __launch_bounds__(256) void qkv_merge(
    const float* __restrict__ P,
    unsigned short* __restrict__ qb, unsigned short* __restrict__ kS,
    unsigned short* __restrict__ vS)
{
  const int gid = blockIdx.x * 256 + threadIdx.x;   // 0..393215
  const size_t e8 = (size_t)gid * 8;
  const int type = (int)(e8 >> 20);                  // 8192*128 = 2^20
  const int rem  = (int)(e8 & 1048575);
  const int m = rem >> 7, n0 = rem & 127;
  const float* p0 = P + (size_t)type * 1048576 + rem;
  const float* p1 = p0 + (size_t)3 * 1048576;
  f32x4 a0 = *reinterpret_cast<const f32x4*>(p0);
  f32x4 a1 = *reinterpret_cast<const f32x4*>(p0 + 4);
  f32x4 b0 = *reinterpret_cast<const f32x4*>(p1);
  f32x4 b1 = *reinterpret_cast<const f32x4*>(p1 + 4);
  float s[8];
  #pragma unroll
  for (int j = 0; j < 4; ++j) { s[j] = a0[j] + b0[j]; s[4 + j] = a1[j] + b1[j]; }
  u32x4 pk = { cvt_pk_bf16(s[0], s[1]), cvt_pk_bf16(s[2], s[3]),
               cvt_pk_bf16(s[4], s[5]), cvt_pk_bf16(s[6], s[7]) };

  const int bb = m >> 12, tt = m & 4095;
  const int kt = tt >> 5, kvl = tt & 31;
  if (type == 0) {
    *reinterpret_cast<u32x4*>(&qb[(size_t)m * HD + n0]) = pk;
  } else if (type == 1) {
    int g = n0 >> 6, hl = n0 & 63;
    int ksf = hl >> 4, r8 = (hl >> 3) & 1;
    size_t idx = ((((((size_t)bb * 128 + kt) * 2 + g) * 4) + ksf) << 9)
               + (size_t)(kvl + 32 * r8) * 8;
    *reinterpret_cast<u32x4*>(&kS[idx]) = pk;
  } else {
    int f = kvl >> 4, r8v = (kvl >> 3) & 1, e = kvl & 7;
    #pragma unroll
    for (int j = 0; j < 8; ++j) {
      int n = n0 + j;
      int vcb = n >> 5;
      size_t idx = (((((size_t)bb * 128 + kt) * 8) + vcb * 2 + f) << 9)
                 + (size_t)((n & 31) + 32 * r8v) * 8 + e;
      vS[idx] = f2bf(s[j]);
    }
  }
}

// ---------------- Kernel 2: per-wave flash partials (unchanged) -----------
template<int LOG2S>
__global__ __launch_bounds__(256, 2) void diff_attn_part(
    const unsigned short* __restrict__ qb, const unsigned short* __restrict__ kS,
    const unsigned short* __restrict__ vS,
    unsigned short* __restrict__ po, float* __restrict__ pm, float* __restrict__ pl)
{
  constexpr int S = 1 << LOG2S;
  const int tid = threadIdx.x, lane = tid & 63, wid = tid >> 6;
  const int wave_id = blockIdx.x * 4 + wid;
  const int sp = wave_id & (S - 1);
  const int g  = (wave_id >> LOG2S) & 1;
  const int qt_raw = (wave_id >> (LOG2S + 1)) & 127;
  const int b  = wave_id >> (LOG2S + 8);
  const int qt = 127 - qt_raw;                  // heavy-first scheduling
  const int slot = (((b * 128 + qt) * 2 + g) << LOG2S) + sp;
  const int lq = lane & 31, lh = lane >> 5;
  const int q0 = qt * 32;
  const int n  = qt + 1;
  const int kt0 = (n * sp) >> LOG2S;
  const int kt1 = (n * (sp + 1)) >> LOG2S;

  bf16x8 qf[4];
  const unsigned short* qp = qb + ((size_t)b * T_SEQ + q0 + lq) * HD + g * 64 + lh * 8;
  #pragma unroll
  for (int ks = 0; ks < 4; ++ks) qf[ks] = *reinterpret_cast<const bf16x8*>(qp + ks * 16);

  f32x16 acc[4];
  #pragma unroll
  for (int v = 0; v < 4; ++v)
    #pragma unroll
    for (int r = 0; r < 16; ++r) acc[v][r] = 0.f;
  float mrun = -1e30f, lrun = 0.f;

  const unsigned short* kbase = kS + ((size_t)(b * 128) * 2 + g) * 4 * 512 + lane * 8;
  const unsigned short* vbase = vS + (size_t)(b * 128) * 8 * 512 + lane * 8;
  #define KFRAG(kt, ks) (kbase + ((size_t)(kt) * 8 + (ks)) * 512)
  #define VFRAG(kt, f)  (vbase + ((size_t)(kt) * 8 + (f)) * 512)

  bf16x8 kf[4];
  if (kt0 < kt1) {
    #pragma unroll
    for (int ks = 0; ks < 4; ++ks)
      kf[ks] = *reinterpret_cast<const bf16x8*>(KFRAG(kt0, ks));
  }

  for (int kt = kt0; kt < kt1; ++kt) {
    bf16x8 vfa[4], vfb[4];
    #pragma unroll
    for (int vcb = 0; vcb < 4; ++vcb) {
      vfa[vcb] = *reinterpret_cast<const bf16x8*>(VFRAG(kt, vcb * 2));
      vfb[vcb] = *reinterpret_cast<const bf16x8*>(VFRAG(kt, vcb * 2 + 1));
    }
    bf16x8 kfn[4];
    const bool more = (kt + 1 < kt1);
    if (more) {
      #pragma unroll
      for (int ks = 0; ks < 4; ++ks)
        kfn[ks] = *reinterpret_cast<const bf16x8*>(KFRAG(kt + 1, ks));
    }
    f32x16 sc;
    #pragma unroll
    for (int r = 0; r < 16; ++r) sc[r] = 0.f;
    #pragma unroll
    for (int ks = 0; ks < 4; ++ks)
      sc = __builtin_amdgcn_mfma_f32_32x32x16_bf16(kf[ks], qf[ks], sc, 0, 0, 0);

    float p[16];
    if (kt == n - 1) {
      #pragma unroll
      for (int r = 0; r < 16; ++r) {
        int rloc = (r & 3) + 8 * (r >> 2) + 4 * lh;
        p[r] = (rloc > lq) ? -1e30f : sc[r];
      }
    } else {
      #pragma unroll
      for (int r = 0; r < 16; ++r) p[r] = sc[r];
    }
    float t16[16];
    #pragma unroll
    for (int r = 0; r < 16; ++r) t16[r] = p[r];
    #pragma unroll
    for (int st = 8; st >= 1; st >>= 1)
      #pragma unroll
      for (int r = 0; r < 8; ++r)
        if (r < st) t16[r] = fmaxf(t16[r], t16[r + st]);
    float pmax = fmaxf(t16[0], __shfl_xor(t16[0], 32));
    if (__any(pmax > mrun + 8.f)) {
      float mn = fmaxf(mrun, pmax);
      float al = __expf(mrun - mn);
      lrun *= al;
      #pragma unroll
      for (int v = 0; v < 4; ++v)
        #pragma unroll
        for (int r = 0; r < 16; ++r) acc[v][r] *= al;
      mrun = mn;
    }
    float psum;
    {
      float s16[16];
      #pragma unroll
      for (int r = 0; r < 16; ++r) { p[r] = __expf(p[r] - mrun); s16[r] = p[r]; }
      #pragma unroll
      for (int st = 8; st >= 1; st >>= 1)
        #pragma unroll
        for (int r = 0; r < 8; ++r)
          if (r < st) s16[r] += s16[r + st];
      psum = s16[0];
    }
    lrun += psum + __shfl_xor(psum, 32);

    unsigned A0 = cvt_pk_bf16(p[0],  p[1]),  A1 = cvt_pk_bf16(p[2],  p[3]);
    unsigned A2 = cvt_pk_bf16(p[4],  p[5]),  A3 = cvt_pk_bf16(p[6],  p[7]);
    unsigned A4 = cvt_pk_bf16(p[8],  p[9]),  A5 = cvt_pk_bf16(p[10], p[11]);
    unsigned A6 = cvt_pk_bf16(p[12], p[13]), A7 = cvt_pk_bf16(p[14], p[15]);
    unsigned pA0 = (unsigned)__shfl_xor((int)A0, 32);
    unsigned pA1 = (unsigned)__shfl_xor((int)A1, 32);
    unsigned pA2 = (unsigned)__shfl_xor((int)A2, 32);
    unsigned pA3 = (unsigned)__shfl_xor((int)A3, 32);
    unsigned pA4 = (unsigned)__shfl_xor((int)A4, 32);
    unsigned pA5 = (unsigned)__shfl_xor((int)A5, 32);
    unsigned pA6 = (unsigned)__shfl_xor((int)A6, 32);
    unsigned pA7 = (unsigned)__shfl_xor((int)A7, 32);
    u32x4 w0, w1;
    w0[0] = lh ? pA2 : A0;  w0[1] = lh ? pA3 : A1;
    w0[2] = lh ? A2  : pA0; w0[3] = lh ? A3  : pA1;
    w1[0] = lh ? pA6 : A4;  w1[1] = lh ? pA7 : A5;
    w1[2] = lh ? A6  : pA4; w1[3] = lh ? A7  : pA5;
    bf16x8 pb0 = *reinterpret_cast<bf16x8*>(&w0);
    bf16x8 pb1 = *reinterpret_cast<bf16x8*>(&w1);
    #pragma unroll
    for (int vcb = 0; vcb < 4; ++vcb) {
      acc[vcb] = __builtin_amdgcn_mfma_f32_32x32x16_bf16(vfa[vcb], pb0, acc[vcb], 0, 0, 0);
      acc[vcb] = __builtin_amdgcn_mfma_f32_32x32x16_bf16(vfb[vcb], pb1, acc[vcb], 0, 0, 0);
    }
    if (more) {
      #pragma unroll
      for (int ks = 0; ks < 4; ++ks) kf[ks] = kfn[ks];
    }
  }
  #undef KFRAG
  #undef VFRAG
  const size_t pbase = (size_t)slot * (HD * 32);
  #pragma unroll
  for (int vcb = 0; vcb < 4; ++vcb)
    #pragma unroll
    for (int r = 0; r < 16; ++r) {
      int vc = vcb * 32 + (r & 3) + 8 * (r >> 2) + 4 * lh;
      po[pbase + (size_t)vc * 32 + lq] = f2bf(acc[vcb][r]);
    }
  if (lane < 32) {
    pm[slot * 32 + lq] = mrun;
    pl[slot * 32 + lq] = lrun;
  }
}

// ---------------- Kernel 3: merge partials (unchanged) --------------------
template<int LOG2S>
__global__ __launch_bounds__(256) void diff_merge(
    const unsigned short* __restrict__ po, const float* __restrict__ pm,
    const float* __restrict__ pl,
    const float* __restrict__ lq1, const float* __restrict__ lq2,
    const float* __restrict__ lk1, const float* __restrict__ lk2,
    const float* __restrict__ lnw, float* __restrict__ out)
{
  constexpr int S = 1 << LOG2S;
  __shared__ float red[4][32];
  const int tid = threadIdx.x, lane = tid & 63, wid = tid >> 6;
  const int q = tid & 31, vg = tid >> 5;
  const int bq = blockIdx.x;
  const int b = bq >> 7, qt = bq & 127;

  float la = lq1[lane] * lk1[lane];
  float lb = lq2[lane] * lk2[lane];
  #pragma unroll
  for (int off = 32; off >= 1; off >>= 1) {
    la += __shfl_xor(la, off);
    lb += __shfl_xor(lb, off);
  }
  const float lam = __expf(la) - __expf(lb) + LAMBDA_INIT;

  const int p1 = (bq * 2 + 0) * S;
  const int p2 = (bq * 2 + 1) * S;
  float w1[S], w2[S];
  {
    float ms[S];
    #pragma unroll
    for (int s = 0; s < S; ++s) ms[s] = pm[(p1 + s) * 32 + q];
    float M = ms[0];
    #pragma unroll
    for (int s = 1; s < S; ++s) M = fmaxf(M, ms[s]);
    float L = 0.f;
    #pragma unroll
    for (int s = 0; s < S; ++s) { w1[s] = __expf(ms[s] - M); L += w1[s] * pl[(p1 + s) * 32 + q]; }
    float inv = 1.f / L;
    #pragma unroll
    for (int s = 0; s < S; ++s) w1[s] *= inv;
  }
  {
    float ms[S];
    #pragma unroll
    for (int s = 0; s < S; ++s) ms[s] = pm[(p2 + s) * 32 + q];
    float M = ms[0];
    #pragma unroll
    for (int s = 1; s < S; ++s) M = fmaxf(M, ms[s]);
    float L = 0.f;
    #pragma unroll
    for (int s = 0; s < S; ++s) { w2[s] = __expf(ms[s] - M); L += w2[s] * pl[(p2 + s) * 32 + q]; }
    float inv = lam / L;
    #pragma unroll
    for (int s = 0; s < S; ++s) w2[s] *= inv;
  }
  float d[16], ss = 0.f;
  #pragma unroll
  for (int i = 0; i < 16; ++i) {
    int vc = vg * 16 + i;
    float a1 = 0.f, a2 = 0.f;
    #pragma unroll
    for (int s = 0; s < S; ++s) {
      a1 += w1[s] * bf2f(po[(size_t)(p1 + s) * (HD * 32) + (size_t)vc * 32 + q]);
      a2 += w2[s] * bf2f(po[(size_t)(p2 + s) * (HD * 32) + (size_t)vc * 32 + q]);
    }
    d[i] = a1 - a2;
    ss += d[i] * d[i];
  }
  ss += __shfl_xor(ss, 32);
  if (lane < 32) red[wid][q] = ss;
  __syncthreads();
  float tot = red[0][q] + red[1][q] + red[2][q] + red[3][q];
  float rinv = 1.f / sqrtf(tot * (1.0f / HD) + 1e-5f);
  float* op = out + ((size_t)b * T_SEQ + qt * 32 + q) * HD + vg * 16;
  #pragma unroll
  for (int i = 0; i < 16; ++i) op[i] = OUT_SCALE * d[i] * rinv * lnw[vg * 16 + i];
}

extern "C" void kernel_launch(void* const* d_in, const int* in_sizes, int n_in,
                              void* d_out, int out_size, void* d_ws, size_t ws_size,
                              hipStream_t stream) {
  const float* x   = (const float*)d_in[0];
  const float* wq  = (const float*)d_in[1];
  const float* wk  = (const float*)d_in[2];
  const float* wv  = (const float*)d_in[3];
  const float* lq1 = (const float*)d_in[4];
  const float* lq2 = (const float*)d_in[5];
  const float* lk1 = (const float*)d_in[6];
  const float* lk2 = (const float*)d_in[7];
  const float* lnw = (const float*)d_in[8];
  float* out = (float*)d_out;

  const size_t N = (size_t)NB * T_SEQ * HD;               // 1,048,576
  const size_t WTN = (size_t)3 * 32 * 8192;               // 786,432 ushorts
  const size_t PB  = (size_t)2 * 3 * 8192 * 128 * 4;      // 25 MB f32 partials
  int log2S = 3;
  size_t parts = 0, region = 0;
  for (;; --log2S) {
    parts = ((size_t)NB * 128 * 2) << log2S;
    size_t pob = parts * (HD * 32) * 2;
    size_t rmin = PB + WTN * 2;
    region = (pob > rmin) ? pob : rmin;
    size_t need = 3 * N * 2 + region + parts * 32 * 8;
    if (need <= ws_size || log2S == 0) break;
  }

  unsigned short* qb = (unsigned short*)d_ws;
  unsigned short* kS = qb + N;
  unsigned short* vS = kS + N;
  unsigned short* po = vS + N;                  // region of `region` bytes
  float* Ppart = (float*)po;                    // dead before attn writes po
  unsigned short* wT = (unsigned short*)((char*)po + region) - WTN;  // tail alias
  float* pm = (float*)((char*)po + region);
  float* pl = pm + parts * 32;

  wtrans<<<dim3(32, 3), 256, 0, stream>>>(wq, wk, wv, wT);
  qkv_part<<<dim3(768), 256, 0, stream>>>(x, wT, Ppart);
  qkv_merge<<<dim3(1536), 256, 0, stream>>>(Ppart, qb, kS, vS);
  const int ablocks = (int)(parts / 4);
  switch (log2S) {
    case 3:
      diff_attn_part<3><<<dim3(ablocks), 256, 0, stream>>>(qb, kS, vS, po, pm, pl);
      diff_merge<3><<<dim3(NB * 128), 256, 0, stream>>>(po, pm, pl, lq1, lq2, lk1, lk2, lnw, out);
      break;
    case 2:
      diff_attn_part<2><<<dim3(ablocks), 256, 0, stream>>>(qb, kS, vS, po, pm, pl);
      diff_merge<2><<<dim3(NB * 128), 256, 0, stream>>>(po, pm, pl, lq1, lq2, lk1, lk2, lnw, out);
      break;
    case 1:
      diff_attn_part<1><<<dim3(ablocks), 256, 0, stream>>>(qb, kS, vS, po, pm, pl);
      diff_merge<1><<<dim3(NB * 128), 256, 0, stream>>>(po, pm, pl, lq1, lq2, lk1, lk2, lnw, out);
      break;
    default:
      diff_attn_part<0><<<dim3(ablocks), 256, 0, stream>>>(qb, kS, vS, po, pm, pl);
      diff_merge<0><<<dim3(NB * 128), 256, 0, stream>>>(po, pm, pl, lq1, lq2, lk1, lk2, lnw, out);
      break;
  }
}

// Round 13
// 89.382 us; speedup vs baseline: 1.2416x; 1.2416x over previous
//
#include <hip/hip_runtime.h>
#include <stdint.h>

#define T_SEQ 4096
#define NB 2
#define D_MODEL 2048
#define HD 128

typedef __attribute__((ext_vector_type(4)))  float f32x4;
typedef __attribute__((ext_vector_type(16))) float f32x16;
typedef __attribute__((ext_vector_type(8)))  short bf16x8;
typedef __attribute__((ext_vector_type(4)))  unsigned u32x4;

#define LAMBDA_INIT 0.7836057665316244f
#define OUT_SCALE   0.21639423346837556f

__device__ __forceinline__ unsigned short f2bf(float f) {
  unsigned int u = __float_as_uint(f);
  u += 0x7FFFu + ((u >> 16) & 1u);
  return (unsigned short)(u >> 16);
}
__device__ __forceinline__ float bf2f(unsigned short h) {
  return __uint_as_float(((unsigned int)h) << 16);
}
__device__ __forceinline__ unsigned cvt_pk_bf16(float a, float b) {
  unsigned r;
  asm("v_cvt_pk_bf16_f32 %0, %1, %2" : "=v"(r) : "v"(a), "v"(b));
  return r;
}
__device__ __forceinline__ void gload16(const void* g, void* l) {
  __builtin_amdgcn_global_load_lds(
      (const __attribute__((address_space(1))) unsigned int*)g,
      (__attribute__((address_space(3))) unsigned int*)l, 16, 0, 0);
}

// ---------------- Kernel 0: pre-pack W into fragment-ordered bf16 ---------
__global__ __launch_bounds__(256) void wtrans(
    const float* __restrict__ wq, const float* __restrict__ wk,
    const float* __restrict__ wv, unsigned short* __restrict__ wT)
{
  const int which = blockIdx.y;
  const int s = blockIdx.x;                     // k-slab 0..31
  const float* w = (which == 0) ? wq : ((which == 1) ? wk : wv);
  const float scale = (which == 0) ? 0.125f : 1.0f;
  const int tid = threadIdx.x;
  #pragma unroll
  for (int j = 0; j < 4; ++j) {
    int cell = j * 256 + tid;                   // 0..1023
    int q = cell >> 7, n = cell & 127;
    int kb = s * 64 + q * 8;
    float v[8];
    #pragma unroll
    for (int e = 0; e < 8; ++e) v[e] = w[(size_t)(kb + e) * HD + n] * scale;
    u32x4 pk = { cvt_pk_bf16(v[0], v[1]), cvt_pk_bf16(v[2], v[3]),
                 cvt_pk_bf16(v[4], v[5]), cvt_pk_bf16(v[6], v[7]) };
    *reinterpret_cast<u32x4*>(&wT[(size_t)(which * 32 + s) * 8192 + (size_t)cell * 8]) = pk;
  }
}

// ---------------- Kernel 1a: QKV K-split partials (full-DMA pipeline) -----
// grid 768: (mt 128) x (type 3) x (ks 2). Tile M=64 x N=128 x K=1024.
// BOTH operands staged by global_load_lds into a 4-slot ring; the ONLY
// vmem waits are explicit positional vmcnt(8/4/0) -> prefetch survives
// barriers (T3/T4). A is f32 [row][kc] with kc^(row&7) swizzle applied on
// the global SOURCE and on the LDS READ (rule 21); bf16 cvt at consume.
// B is bf16 k-major [kg 4][n 128] (R8-proven conflict-free), linear DMA.
__global__ __launch_bounds__(256, 2) void qkv_part(
    const float* __restrict__ x, const unsigned short* __restrict__ wT,
    float* __restrict__ P)
{
  __shared__ __align__(16) char lds[4][16384];  // slot: A 8KB (f32) + B 8KB (bf16)
  const int tid = threadIdx.x, lane = tid & 63, wid = tid >> 6;
  const int bid = blockIdx.x;
  const int ks   = bid & 1;
  const int type = (bid >> 1) % 3;
  const int mt   = bid / 6;
  const int wm = wid >> 1, wn = wid & 1;        // wave tile 32(m) x 64(n)
  const int fr = lane & 15, fq = lane >> 4;
  const int m0 = mt * 64;

  const float* xbase = x + (size_t)m0 * D_MODEL + ks * 1024;
  const unsigned short* wslab = wT + (size_t)type * 262144 + (size_t)(ks * 16) * 8192;

  f32x4 acc[2][4];
  #pragma unroll
  for (int i = 0; i < 2; ++i)
    #pragma unroll
    for (int j = 0; j < 4; ++j) acc[i][j] = (f32x4){0.f, 0.f, 0.f, 0.f};

// DMA for K-step t into slot t&3. Per wave: 2 A-instr + 2 B-instr.
#define DMA(t) do {                                                        \
    char* As_ = &lds[(t) & 3][0];                                          \
    char* Bs_ = &lds[(t) & 3][8192];                                       \
    const int k0_ = (t) * 32;                                              \
    _Pragma("unroll")                                                      \
    for (int j = 0; j < 2; ++j) {                                          \
      int c = (wid * 2 + j) * 64 + lane;                                   \
      int row = c >> 3, kcp = c & 7;                                       \
      gload16(xbase + (size_t)row * D_MODEL + k0_ + ((kcp ^ (row & 7)) << 2), \
              As_ + (wid * 2 + j) * 1024);                                 \
    }                                                                      \
    const unsigned short* bsrc_ = wslab + (size_t)(t) * 4096;              \
    _Pragma("unroll")                                                      \
    for (int j = 0; j < 2; ++j) {                                          \
      int cb = (wid * 2 + j) * 64;                                         \
      gload16(bsrc_ + (size_t)(cb + lane) * 8, Bs_ + cb * 16);             \
    }                                                                      \
  } while (0)

#define STEP(t, VMIMM) do {                                                \
    asm volatile("s_waitcnt vmcnt(" VMIMM ")" ::: "memory");               \
    __builtin_amdgcn_s_barrier();                                          \
    __builtin_amdgcn_sched_barrier(0);                                     \
    if ((t) + 3 < 32) DMA((t) + 3);                                        \
    __builtin_amdgcn_sched_barrier(0);                                     \
    const char* Ac_ = &lds[(t) & 3][0];                                    \
    const char* Bc_ = &lds[(t) & 3][8192];                                 \
    bf16x8 af_[2];                                                         \
    _Pragma("unroll")                                                      \
    for (int mi = 0; mi < 2; ++mi) {                                       \
      int row = wm * 32 + mi * 16 + fr;                                    \
      int p1 = (2 * fq) ^ (row & 7), p2 = (2 * fq + 1) ^ (row & 7);        \
      f32x4 lo = *reinterpret_cast<const f32x4*>(Ac_ + (row * 8 + p1) * 16); \
      f32x4 hi = *reinterpret_cast<const f32x4*>(Ac_ + (row * 8 + p2) * 16); \
      u32x4 pk = { cvt_pk_bf16(lo[0], lo[1]), cvt_pk_bf16(lo[2], lo[3]),   \
                   cvt_pk_bf16(hi[0], hi[1]), cvt_pk_bf16(hi[2], hi[3]) }; \
      af_[mi] = *reinterpret_cast<bf16x8*>(&pk);                           \
    }                                                                      \
    _Pragma("unroll")                                                      \
    for (int ni = 0; ni < 4; ++ni) {                                       \
      int n = wn * 64 + ni * 16 + fr;                                      \
      bf16x8 bf_ = *reinterpret_cast<const bf16x8*>(Bc_ + (fq * 128 + n) * 16); \
      acc[0][ni] = __builtin_amdgcn_mfma_f32_16x16x32_bf16(af_[0], bf_, acc[0][ni], 0, 0, 0); \
      acc[1][ni] = __builtin_amdgcn_mfma_f32_16x16x32_bf16(af_[1], bf_, acc[1][ni], 0, 0, 0); \
    }                                                                      \
  } while (0)

  DMA(0); DMA(1); DMA(2);
  #pragma unroll 1
  for (int t = 0; t < 30; ++t) STEP(t, "8");
  STEP(30, "4");
  STEP(31, "0");
#undef STEP
#undef DMA

  // partial store: P[((ks*3+type)*8192 + m)*128 + n]
  float* pp = P + ((size_t)(ks * 3 + type) * 8192 + m0) * 128;
  #pragma unroll
  for (int mi = 0; mi < 2; ++mi)
    #pragma unroll
    for (int ni = 0; ni < 4; ++ni)
      #pragma unroll
      for (int r = 0; r < 4; ++r)
        pp[(size_t)(wm * 32 + mi * 16 + fq * 4 + r) * 128 + wn * 64 + ni * 16 + fr]
            = acc[mi][ni][r];
}

// ---------------- Kernel 1b: merge partials + fragment scatter ------------
__global__ __launch_bounds__(256) void qkv_merge(
    const float* __restrict__ P,
    unsigned short* __restrict__ qb, unsigned short* __restrict__ kS,
    unsigned short* __restrict__ vS)
{
  const int gid = blockIdx.x * 256 + threadIdx.x;   // 0..393215
  const size_t e8 = (size_t)gid * 8;
  const int type = (int)(e8 >> 20);                  // 8192*128 = 2^20
  const int rem  = (int)(e8 & 1048575);
  const int m = rem >> 7, n0 = rem & 127;
  const float* p0 = P + (size_t)type * 1048576 + rem;
  const float* p1 = p0 + (size_t)3 * 1048576;
  f32x4 a0 = *reinterpret_cast<const f32x4*>(p0);
  f32x4 a1 = *reinterpret_cast<const f32x4*>(p0 + 4);
  f32x4 b0 = *reinterpret_cast<const f32x4*>(p1);
  f32x4 b1 = *reinterpret_cast<const f32x4*>(p1 + 4);
  float s[8];
  #pragma unroll
  for (int j = 0; j < 4; ++j) { s[j] = a0[j] + b0[j]; s[4 + j] = a1[j] + b1[j]; }
  u32x4 pk = { cvt_pk_bf16(s[0], s[1]), cvt_pk_bf16(s[2], s[3]),
               cvt_pk_bf16(s[4], s[5]), cvt_pk_bf16(s[6], s[7]) };

  const int bb = m >> 12, tt = m & 4095;
  const int kt = tt >> 5, kvl = tt & 31;
  if (type == 0) {
    *reinterpret_cast<u32x4*>(&qb[(size_t)m * HD + n0]) = pk;
  } else if (type == 1) {
    int g = n0 >> 6, hl = n0 & 63;
    int ksf = hl >> 4, r8 = (hl >> 3) & 1;
    size_t idx = ((((((size_t)bb * 128 + kt) * 2 + g) * 4) + ksf) << 9)
               + (size_t)(kvl + 32 * r8) * 8;
    *reinterpret_cast<u32x4*>(&kS[idx]) = pk;
  } else {
    int f = kvl >> 4, r8v = (kvl >> 3) & 1, e = kvl & 7;
    #pragma unroll
    for (int j = 0; j < 8; ++j) {
      int n = n0 + j;
      int vcb = n >> 5;
      size_t idx = (((((size_t)bb * 128 + kt) * 8) + vcb * 2 + f) << 9)
                 + (size_t)((n & 31) + 32 * r8v) * 8 + e;
      vS[idx] = f2bf(s[j]);
    }
  }
}

// ---------------- Kernel 2: per-wave flash partials (unchanged) -----------
template<int LOG2S>
__global__ __launch_bounds__(256, 2) void diff_attn_part(
    const unsigned short* __restrict__ qb, const unsigned short* __restrict__ kS,
    const unsigned short* __restrict__ vS,
    unsigned short* __restrict__ po, float* __restrict__ pm, float* __restrict__ pl)
{
  constexpr int S = 1 << LOG2S;
  const int tid = threadIdx.x, lane = tid & 63, wid = tid >> 6;
  const int wave_id = blockIdx.x * 4 + wid;
  const int sp = wave_id & (S - 1);
  const int g  = (wave_id >> LOG2S) & 1;
  const int qt_raw = (wave_id >> (LOG2S + 1)) & 127;
  const int b  = wave_id >> (LOG2S + 8);
  const int qt = 127 - qt_raw;                  // heavy-first scheduling
  const int slot = (((b * 128 + qt) * 2 + g) << LOG2S) + sp;
  const int lq = lane & 31, lh = lane >> 5;
  const int q0 = qt * 32;
  const int n  = qt + 1;
  const int kt0 = (n * sp) >> LOG2S;
  const int kt1 = (n * (sp + 1)) >> LOG2S;

  bf16x8 qf[4];
  const unsigned short* qp = qb + ((size_t)b * T_SEQ + q0 + lq) * HD + g * 64 + lh * 8;
  #pragma unroll
  for (int ks = 0; ks < 4; ++ks) qf[ks] = *reinterpret_cast<const bf16x8*>(qp + ks * 16);

  f32x16 acc[4];
  #pragma unroll
  for (int v = 0; v < 4; ++v)
    #pragma unroll
    for (int r = 0; r < 16; ++r) acc[v][r] = 0.f;
  float mrun = -1e30f, lrun = 0.f;

  const unsigned short* kbase = kS + ((size_t)(b * 128) * 2 + g) * 4 * 512 + lane * 8;
  const unsigned short* vbase = vS + (size_t)(b * 128) * 8 * 512 + lane * 8;
  #define KFRAG(kt, ks) (kbase + ((size_t)(kt) * 8 + (ks)) * 512)
  #define VFRAG(kt, f)  (vbase + ((size_t)(kt) * 8 + (f)) * 512)

  bf16x8 kf[4];
  if (kt0 < kt1) {
    #pragma unroll
    for (int ks = 0; ks < 4; ++ks)
      kf[ks] = *reinterpret_cast<const bf16x8*>(KFRAG(kt0, ks));
  }

  for (int kt = kt0; kt < kt1; ++kt) {
    bf16x8 vfa[4], vfb[4];
    #pragma unroll
    for (int vcb = 0; vcb < 4; ++vcb) {
      vfa[vcb] = *reinterpret_cast<const bf16x8*>(VFRAG(kt, vcb * 2));
      vfb[vcb] = *reinterpret_cast<const bf16x8*>(VFRAG(kt, vcb * 2 + 1));
    }
    bf16x8 kfn[4];
    const bool more = (kt + 1 < kt1);
    if (more) {
      #pragma unroll
      for (int ks = 0; ks < 4; ++ks)
        kfn[ks] = *reinterpret_cast<const bf16x8*>(KFRAG(kt + 1, ks));
    }
    f32x16 sc;
    #pragma unroll
    for (int r = 0; r < 16; ++r) sc[r] = 0.f;
    #pragma unroll
    for (int ks = 0; ks < 4; ++ks)
      sc = __builtin_amdgcn_mfma_f32_32x32x16_bf16(kf[ks], qf[ks], sc, 0, 0, 0);

    float p[16];
    if (kt == n - 1) {
      #pragma unroll
      for (int r = 0; r < 16; ++r) {
        int rloc = (r & 3) + 8 * (r >> 2) + 4 * lh;
        p[r] = (rloc > lq) ? -1e30f : sc[r];
      }
    } else {
      #pragma unroll
      for (int r = 0; r < 16; ++r) p[r] = sc[r];
    }
    float t16[16];
    #pragma unroll
    for (int r = 0; r < 16; ++r) t16[r] = p[r];
    #pragma unroll
    for (int st = 8; st >= 1; st >>= 1)
      #pragma unroll
      for (int r = 0; r < 8; ++r)
        if (r < st) t16[r] = fmaxf(t16[r], t16[r + st]);
    float pmax = fmaxf(t16[0], __shfl_xor(t16[0], 32));
    if (__any(pmax > mrun + 8.f)) {
      float mn = fmaxf(mrun, pmax);
      float al = __expf(mrun - mn);
      lrun *= al;
      #pragma unroll
      for (int v = 0; v < 4; ++v)
        #pragma unroll
        for (int r = 0; r < 16; ++r) acc[v][r] *= al;
      mrun = mn;
    }
    float psum;
    {
      float s16[16];
      #pragma unroll
      for (int r = 0; r < 16; ++r) { p[r] = __expf(p[r] - mrun); s16[r] = p[r]; }
      #pragma unroll
      for (int st = 8; st >= 1; st >>= 1)
        #pragma unroll
        for (int r = 0; r < 8; ++r)
          if (r < st) s16[r] += s16[r + st];
      psum = s16[0];
    }
    lrun += psum + __shfl_xor(psum, 32);

    unsigned A0 = cvt_pk_bf16(p[0],  p[1]),  A1 = cvt_pk_bf16(p[2],  p[3]);
    unsigned A2 = cvt_pk_bf16(p[4],  p[5]),  A3 = cvt_pk_bf16(p[6],  p[7]);
    unsigned A4 = cvt_pk_bf16(p[8],  p[9]),  A5 = cvt_pk_bf16(p[10], p[11]);
    unsigned A6 = cvt_pk_bf16(p[12], p[13]), A7 = cvt_pk_bf16(p[14], p[15]);
    unsigned pA0 = (unsigned)__shfl_xor((int)A0, 32);
    unsigned pA1 = (unsigned)__shfl_xor((int)A1, 32);
    unsigned pA2 = (unsigned)__shfl_xor((int)A2, 32);
    unsigned pA3 = (unsigned)__shfl_xor((int)A3, 32);
    unsigned pA4 = (unsigned)__shfl_xor((int)A4, 32);
    unsigned pA5 = (unsigned)__shfl_xor((int)A5, 32);
    unsigned pA6 = (unsigned)__shfl_xor((int)A6, 32);
    unsigned pA7 = (unsigned)__shfl_xor((int)A7, 32);
    u32x4 w0, w1;
    w0[0] = lh ? pA2 : A0;  w0[1] = lh ? pA3 : A1;
    w0[2] = lh ? A2  : pA0; w0[3] = lh ? A3  : pA1;
    w1[0] = lh ? pA6 : A4;  w1[1] = lh ? pA7 : A5;
    w1[2] = lh ? A6  : pA4; w1[3] = lh ? A7  : pA5;
    bf16x8 pb0 = *reinterpret_cast<bf16x8*>(&w0);
    bf16x8 pb1 = *reinterpret_cast<bf16x8*>(&w1);
    #pragma unroll
    for (int vcb = 0; vcb < 4; ++vcb) {
      acc[vcb] = __builtin_amdgcn_mfma_f32_32x32x16_bf16(vfa[vcb], pb0, acc[vcb], 0, 0, 0);
      acc[vcb] = __builtin_amdgcn_mfma_f32_32x32x16_bf16(vfb[vcb], pb1, acc[vcb], 0, 0, 0);
    }
    if (more) {
      #pragma unroll
      for (int ks = 0; ks < 4; ++ks) kf[ks] = kfn[ks];
    }
  }
  #undef KFRAG
  #undef VFRAG
  const size_t pbase = (size_t)slot * (HD * 32);
  #pragma unroll
  for (int vcb = 0; vcb < 4; ++vcb)
    #pragma unroll
    for (int r = 0; r < 16; ++r) {
      int vc = vcb * 32 + (r & 3) + 8 * (r >> 2) + 4 * lh;
      po[pbase + (size_t)vc * 32 + lq] = f2bf(acc[vcb][r]);
    }
  if (lane < 32) {
    pm[slot * 32 + lq] = mrun;
    pl[slot * 32 + lq] = lrun;
  }
}

// ---------------- Kernel 3: merge partials (unchanged) --------------------
template<int LOG2S>
__global__ __launch_bounds__(256) void diff_merge(
    const unsigned short* __restrict__ po, const float* __restrict__ pm,
    const float* __restrict__ pl,
    const float* __restrict__ lq1, const float* __restrict__ lq2,
    const float* __restrict__ lk1, const float* __restrict__ lk2,
    const float* __restrict__ lnw, float* __restrict__ out)
{
  constexpr int S = 1 << LOG2S;
  __shared__ float red[4][32];
  const int tid = threadIdx.x, lane = tid & 63, wid = tid >> 6;
  const int q = tid & 31, vg = tid >> 5;
  const int bq = blockIdx.x;
  const int b = bq >> 7, qt = bq & 127;

  float la = lq1[lane] * lk1[lane];
  float lb = lq2[lane] * lk2[lane];
  #pragma unroll
  for (int off = 32; off >= 1; off >>= 1) {
    la += __shfl_xor(la, off);
    lb += __shfl_xor(lb, off);
  }
  const float lam = __expf(la) - __expf(lb) + LAMBDA_INIT;

  const int p1 = (bq * 2 + 0) * S;
  const int p2 = (bq * 2 + 1) * S;
  float w1[S], w2[S];
  {
    float ms[S];
    #pragma unroll
    for (int s = 0; s < S; ++s) ms[s] = pm[(p1 + s) * 32 + q];
    float M = ms[0];
    #pragma unroll
    for (int s = 1; s < S; ++s) M = fmaxf(M, ms[s]);
    float L = 0.f;
    #pragma unroll
    for (int s = 0; s < S; ++s) { w1[s] = __expf(ms[s] - M); L += w1[s] * pl[(p1 + s) * 32 + q]; }
    float inv = 1.f / L;
    #pragma unroll
    for (int s = 0; s < S; ++s) w1[s] *= inv;
  }
  {
    float ms[S];
    #pragma unroll
    for (int s = 0; s < S; ++s) ms[s] = pm[(p2 + s) * 32 + q];
    float M = ms[0];
    #pragma unroll
    for (int s = 1; s < S; ++s) M = fmaxf(M, ms[s]);
    float L = 0.f;
    #pragma unroll
    for (int s = 0; s < S; ++s) { w2[s] = __expf(ms[s] - M); L += w2[s] * pl[(p2 + s) * 32 + q]; }
    float inv = lam / L;
    #pragma unroll
    for (int s = 0; s < S; ++s) w2[s] *= inv;
  }
  float d[16], ss = 0.f;
  #pragma unroll
  for (int i = 0; i < 16; ++i) {
    int vc = vg * 16 + i;
    float a1 = 0.f, a2 = 0.f;
    #pragma unroll
    for (int s = 0; s < S; ++s) {
      a1 += w1[s] * bf2f(po[(size_t)(p1 + s) * (HD * 32) + (size_t)vc * 32 + q]);
      a2 += w2[s] * bf2f(po[(size_t)(p2 + s) * (HD * 32) + (size_t)vc * 32 + q]);
    }
    d[i] = a1 - a2;
    ss += d[i] * d[i];
  }
  ss += __shfl_xor(ss, 32);
  if (lane < 32) red[wid][q] = ss;
  __syncthreads();
  float tot = red[0][q] + red[1][q] + red[2][q] + red[3][q];
  float rinv = 1.f / sqrtf(tot * (1.0f / HD) + 1e-5f);
  float* op = out + ((size_t)b * T_SEQ + qt * 32 + q) * HD + vg * 16;
  #pragma unroll
  for (int i = 0; i < 16; ++i) op[i] = OUT_SCALE * d[i] * rinv * lnw[vg * 16 + i];
}

extern "C" void kernel_launch(void* const* d_in, const int* in_sizes, int n_in,
                              void* d_out, int out_size, void* d_ws, size_t ws_size,
                              hipStream_t stream) {
  const float* x   = (const float*)d_in[0];
  const float* wq  = (const float*)d_in[1];
  const float* wk  = (const float*)d_in[2];
  const float* wv  = (const float*)d_in[3];
  const float* lq1 = (const float*)d_in[4];
  const float* lq2 = (const float*)d_in[5];
  const float* lk1 = (const float*)d_in[6];
  const float* lk2 = (const float*)d_in[7];
  const float* lnw = (const float*)d_in[8];
  float* out = (float*)d_out;

  const size_t N = (size_t)NB * T_SEQ * HD;               // 1,048,576
  const size_t WTN = (size_t)3 * 32 * 8192;               // 786,432 ushorts
  const size_t PB  = (size_t)2 * 3 * 8192 * 128 * 4;      // 25 MB f32 partials
  int log2S = 3;
  size_t parts = 0, region = 0;
  for (;; --log2S) {
    parts = ((size_t)NB * 128 * 2) << log2S;
    size_t pob = parts * (HD * 32) * 2;
    size_t rmin = PB + WTN * 2;
    region = (pob > rmin) ? pob : rmin;
    size_t need = 3 * N * 2 + region + parts * 32 * 8;
    if (need <= ws_size || log2S == 0) break;
  }

  unsigned short* qb = (unsigned short*)d_ws;
  unsigned short* kS = qb + N;
  unsigned short* vS = kS + N;
  unsigned short* po = vS + N;                  // region of `region` bytes
  float* Ppart = (float*)po;                    // dead before attn writes po
  unsigned short* wT = (unsigned short*)((char*)po + region) - WTN;  // tail alias
  float* pm = (float*)((char*)po + region);
  float* pl = pm + parts * 32;

  wtrans<<<dim3(32, 3), 256, 0, stream>>>(wq, wk, wv, wT);
  qkv_part<<<dim3(768), 256, 0, stream>>>(x, wT, Ppart);
  qkv_merge<<<dim3(1536), 256, 0, stream>>>(Ppart, qb, kS, vS);
  const int ablocks = (int)(parts / 4);
  switch (log2S) {
    case 3:
      diff_attn_part<3><<<dim3(ablocks), 256, 0, stream>>>(qb, kS, vS, po, pm, pl);
      diff_merge<3><<<dim3(NB * 128), 256, 0, stream>>>(po, pm, pl, lq1, lq2, lk1, lk2, lnw, out);
      break;
    case 2:
      diff_attn_part<2><<<dim3(ablocks), 256, 0, stream>>>(qb, kS, vS, po, pm, pl);
      diff_merge<2><<<dim3(NB * 128), 256, 0, stream>>>(po, pm, pl, lq1, lq2, lk1, lk2, lnw, out);
      break;
    case 1:
      diff_attn_part<1><<<dim3(ablocks), 256, 0, stream>>>(qb, kS, vS, po, pm, pl);
      diff_merge<1><<<dim3(NB * 128), 256, 0, stream>>>(po, pm, pl, lq1, lq2, lk1, lk2, lnw, out);
      break;
    default:
      diff_attn_part<0><<<dim3(ablocks), 256, 0, stream>>>(qb, kS, vS, po, pm, pl);
      diff_merge<0><<<dim3(NB * 128), 256, 0, stream>>>(po, pm, pl, lq1, lq2, lk1, lk2, lnw, out);
      break;
  }
}

// Round 15
// 79.577 us; speedup vs baseline: 1.3946x; 1.1232x over previous
//
#include <hip/hip_runtime.h>
#include <stdint.h>

#define T_SEQ 4096
#define NB 2
#define D_MODEL 2048
#define HD 128

typedef __attribute__((ext_vector_type(4)))  float f32x4;
typedef __attribute__((ext_vector_type(16))) float f32x16;
typedef __attribute__((ext_vector_type(8)))  short bf16x8;
typedef __attribute__((ext_vector_type(4)))  unsigned u32x4;

#define LAMBDA_INIT 0.7836057665316244f
#define OUT_SCALE   0.21639423346837556f

__device__ __forceinline__ unsigned short f2bf(float f) {
  unsigned int u = __float_as_uint(f);
  u += 0x7FFFu + ((u >> 16) & 1u);
  return (unsigned short)(u >> 16);
}
__device__ __forceinline__ float bf2f(unsigned short h) {
  return __uint_as_float(((unsigned int)h) << 16);
}
__device__ __forceinline__ unsigned cvt_pk_bf16(float a, float b) {
  unsigned r;
  asm("v_cvt_pk_bf16_f32 %0, %1, %2" : "=v"(r) : "v"(a), "v"(b));
  return r;
}
__device__ __forceinline__ void gload16(const void* g, void* l) {
  __builtin_amdgcn_global_load_lds(
      (const __attribute__((address_space(1))) unsigned int*)g,
      (__attribute__((address_space(3))) unsigned int*)l, 16, 0, 0);
}

// ---------------- Kernel 0: pre-pack W into fragment-ordered bf16 ---------
__global__ __launch_bounds__(256) void wtrans(
    const float* __restrict__ wq, const float* __restrict__ wk,
    const float* __restrict__ wv, unsigned short* __restrict__ wT)
{
  const int which = blockIdx.y;
  const int s = blockIdx.x;                     // k-slab 0..31
  const float* w = (which == 0) ? wq : ((which == 1) ? wk : wv);
  const float scale = (which == 0) ? 0.125f : 1.0f;
  const int tid = threadIdx.x;
  #pragma unroll
  for (int j = 0; j < 4; ++j) {
    int cell = j * 256 + tid;                   // 0..1023
    int q = cell >> 7, n = cell & 127;
    int kb = s * 64 + q * 8;
    float v[8];
    #pragma unroll
    for (int e = 0; e < 8; ++e) v[e] = w[(size_t)(kb + e) * HD + n] * scale;
    u32x4 pk = { cvt_pk_bf16(v[0], v[1]), cvt_pk_bf16(v[2], v[3]),
                 cvt_pk_bf16(v[4], v[5]), cvt_pk_bf16(v[6], v[7]) };
    *reinterpret_cast<u32x4*>(&wT[(size_t)(which * 32 + s) * 8192 + (size_t)cell * 8]) = pk;
  }
}

// ---------------- Kernel 1a: fused QKV K-split partials (full-DMA) --------
// grid 256: (mt 128) x (ks 2). Block computes q,k,v for 64 rows, K=1024
// (32 steps of 32). x read ONCE. Ring-4 LDS (32KB/slot: A f32 8KB swizzled
// + B bf16 3x8KB), prefetch distance 3 (R13-proven: (t+3)&3 != t&3, so
// the DMA never targets the slot being consumed). Counted vmcnt(16/8/0).
__global__ __launch_bounds__(256, 1) void qkv_part(
    const float* __restrict__ x, const unsigned short* __restrict__ wT,
    float* __restrict__ P)
{
  __shared__ __align__(16) char lds[4][32768];   // 128 KB
  const int tid = threadIdx.x, lane = tid & 63, wid = tid >> 6;
  const int bid = blockIdx.x;
  const int ks = bid & 1;
  const int mt = bid >> 1;
  const int wm = wid >> 1, wn = wid & 1;        // wave tile 32(m) x 64(n)
  const int fr = lane & 15, fq = lane >> 4;
  const int m0 = mt * 64;

  const float* xbase = x + (size_t)m0 * D_MODEL + ks * 1024;
  const unsigned short* wbase = wT + (size_t)(ks * 16) * 8192;  // +type*262144

  f32x4 acc[3][2][4];
  #pragma unroll
  for (int ty = 0; ty < 3; ++ty)
    #pragma unroll
    for (int i = 0; i < 2; ++i)
      #pragma unroll
      for (int j = 0; j < 4; ++j) acc[ty][i][j] = (f32x4){0.f, 0.f, 0.f, 0.f};

// DMA step t into slot t&3. Per wave: 2 A + 6 B = 8 instructions.
#define DMA(t) do {                                                        \
    char* As_ = &lds[(t) & 3][0];                                          \
    char* Bs_ = &lds[(t) & 3][8192];                                       \
    const int k0_ = (t) * 32;                                              \
    _Pragma("unroll")                                                      \
    for (int j = 0; j < 2; ++j) {                                          \
      int c = (wid * 2 + j) * 64 + lane;                                   \
      int row = c >> 3, kcp = c & 7;                                       \
      gload16(xbase + (size_t)row * D_MODEL + k0_ + ((kcp ^ (row & 7)) << 2), \
              As_ + (wid * 2 + j) * 1024);                                 \
    }                                                                      \
    _Pragma("unroll")                                                      \
    for (int ty = 0; ty < 3; ++ty) {                                       \
      const unsigned short* bs_ = wbase + (size_t)ty * 262144              \
                                + (size_t)((t) >> 1) * 8192                \
                                + (size_t)((t) & 1) * 4096;                \
      _Pragma("unroll")                                                    \
      for (int j = 0; j < 2; ++j) {                                        \
        int cb = (wid * 2 + j) * 64;                                       \
        gload16(bs_ + (size_t)(cb + lane) * 8,                             \
                Bs_ + (size_t)ty * 8192 + cb * 16);                        \
      }                                                                    \
    }                                                                      \
  } while (0)

#define STEP(t, VMIMM) do {                                                \
    asm volatile("s_waitcnt vmcnt(" VMIMM ")" ::: "memory");               \
    __builtin_amdgcn_s_barrier();                                          \
    __builtin_amdgcn_sched_barrier(0);                                     \
    if ((t) + 3 < 32) DMA((t) + 3);                                        \
    __builtin_amdgcn_sched_barrier(0);                                     \
    const char* Ac_ = &lds[(t) & 3][0];                                    \
    const char* Bc_ = &lds[(t) & 3][8192];                                 \
    bf16x8 af_[2];                                                         \
    _Pragma("unroll")                                                      \
    for (int mi = 0; mi < 2; ++mi) {                                       \
      int row = wm * 32 + mi * 16 + fr;                                    \
      int p1 = (2 * fq) ^ (row & 7), p2 = (2 * fq + 1) ^ (row & 7);        \
      f32x4 lo = *reinterpret_cast<const f32x4*>(Ac_ + (row * 8 + p1) * 16); \
      f32x4 hi = *reinterpret_cast<const f32x4*>(Ac_ + (row * 8 + p2) * 16); \
      u32x4 pk = { cvt_pk_bf16(lo[0], lo[1]), cvt_pk_bf16(lo[2], lo[3]),   \
                   cvt_pk_bf16(hi[0], hi[1]), cvt_pk_bf16(hi[2], hi[3]) }; \
      af_[mi] = *reinterpret_cast<bf16x8*>(&pk);                           \
    }                                                                      \
    _Pragma("unroll")                                                      \
    for (int ty = 0; ty < 3; ++ty)                                         \
      _Pragma("unroll")                                                    \
      for (int ni = 0; ni < 4; ++ni) {                                     \
        int n = wn * 64 + ni * 16 + fr;                                    \
        bf16x8 bf_ = *reinterpret_cast<const bf16x8*>(                     \
            Bc_ + (size_t)ty * 8192 + (fq * 128 + n) * 16);                \
        acc[ty][0][ni] = __builtin_amdgcn_mfma_f32_16x16x32_bf16(af_[0], bf_, acc[ty][0][ni], 0, 0, 0); \
        acc[ty][1][ni] = __builtin_amdgcn_mfma_f32_16x16x32_bf16(af_[1], bf_, acc[ty][1][ni], 0, 0, 0); \
      }                                                                    \
  } while (0)

  DMA(0); DMA(1); DMA(2);
  #pragma unroll 1
  for (int t = 0; t < 29; ++t) STEP(t, "16");
  STEP(29, "16");
  STEP(30, "8");
  STEP(31, "0");
#undef STEP
#undef DMA

  // partial store: P[((ks*3+type)*8192 + m)*128 + n]
  #pragma unroll
  for (int ty = 0; ty < 3; ++ty) {
    float* pp = P + ((size_t)(ks * 3 + ty) * 8192 + m0) * 128;
    #pragma unroll
    for (int mi = 0; mi < 2; ++mi)
      #pragma unroll
      for (int ni = 0; ni < 4; ++ni)
        #pragma unroll
        for (int r = 0; r < 4; ++r)
          pp[(size_t)(wm * 32 + mi * 16 + fq * 4 + r) * 128 + wn * 64 + ni * 16 + fr]
              = acc[ty][mi][ni][r];
  }
}

// ---------------- Kernel 1b: merge partials + fragment scatter ------------
__global__ __launch_bounds__(256) void qkv_merge(
    const float* __restrict__ P,
    unsigned short* __restrict__ qb, unsigned short* __restrict__ kS,
    unsigned short* __restrict__ vS)
{
  const int gid = blockIdx.x * 256 + threadIdx.x;   // 0..393215
  const size_t e8 = (size_t)gid * 8;
  const int type = (int)(e8 >> 20);                  // 8192*128 = 2^20
  const int rem  = (int)(e8 & 1048575);
  const int m = rem >> 7, n0 = rem & 127;
  const float* p0 = P + (size_t)type * 1048576 + rem;
  const float* p1 = p0 + (size_t)3 * 1048576;
  f32x4 a0 = *reinterpret_cast<const f32x4*>(p0);
  f32x4 a1 = *reinterpret_cast<const f32x4*>(p0 + 4);
  f32x4 b0 = *reinterpret_cast<const f32x4*>(p1);
  f32x4 b1 = *reinterpret_cast<const f32x4*>(p1 + 4);
  float s[8];
  #pragma unroll
  for (int j = 0; j < 4; ++j) { s[j] = a0[j] + b0[j]; s[4 + j] = a1[j] + b1[j]; }
  u32x4 pk = { cvt_pk_bf16(s[0], s[1]), cvt_pk_bf16(s[2], s[3]),
               cvt_pk_bf16(s[4], s[5]), cvt_pk_bf16(s[6], s[7]) };

  const int bb = m >> 12, tt = m & 4095;
  const int kt = tt >> 5, kvl = tt & 31;
  if (type == 0) {
    *reinterpret_cast<u32x4*>(&qb[(size_t)m * HD + n0]) = pk;
  } else if (type == 1) {
    int g = n0 >> 6, hl = n0 & 63;
    int ksf = hl >> 4, r8 = (hl >> 3) & 1;
    size_t idx = ((((((size_t)bb * 128 + kt) * 2 + g) * 4) + ksf) << 9)
               + (size_t)(kvl + 32 * r8) * 8;
    *reinterpret_cast<u32x4*>(&kS[idx]) = pk;
  } else {
    int f = kvl >> 4, r8v = (kvl >> 3) & 1, e = kvl & 7;
    #pragma unroll
    for (int j = 0; j < 8; ++j) {
      int n = n0 + j;
      int vcb = n >> 5;
      size_t idx = (((((size_t)bb * 128 + kt) * 8) + vcb * 2 + f) << 9)
                 + (size_t)((n & 31) + 32 * r8v) * 8 + e;
      vS[idx] = f2bf(s[j]);
    }
  }
}

// ---------------- Kernel 2: per-wave flash partials (unchanged) -----------
template<int LOG2S>
__global__ __launch_bounds__(256, 2) void diff_attn_part(
    const unsigned short* __restrict__ qb, const unsigned short* __restrict__ kS,
    const unsigned short* __restrict__ vS,
    unsigned short* __restrict__ po, float* __restrict__ pm, float* __restrict__ pl)
{
  constexpr int S = 1 << LOG2S;
  const int tid = threadIdx.x, lane = tid & 63, wid = tid >> 6;
  const int wave_id = blockIdx.x * 4 + wid;
  const int sp = wave_id & (S - 1);
  const int g  = (wave_id >> LOG2S) & 1;
  const int qt_raw = (wave_id >> (LOG2S + 1)) & 127;
  const int b  = wave_id >> (LOG2S + 8);
  const int qt = 127 - qt_raw;                  // heavy-first scheduling
  const int slot = (((b * 128 + qt) * 2 + g) << LOG2S) + sp;
  const int lq = lane & 31, lh = lane >> 5;
  const int q0 = qt * 32;
  const int n  = qt + 1;
  const int kt0 = (n * sp) >> LOG2S;
  const int kt1 = (n * (sp + 1)) >> LOG2S;

  bf16x8 qf[4];
  const unsigned short* qp = qb + ((size_t)b * T_SEQ + q0 + lq) * HD + g * 64 + lh * 8;
  #pragma unroll
  for (int ks = 0; ks < 4; ++ks) qf[ks] = *reinterpret_cast<const bf16x8*>(qp + ks * 16);

  f32x16 acc[4];
  #pragma unroll
  for (int v = 0; v < 4; ++v)
    #pragma unroll
    for (int r = 0; r < 16; ++r) acc[v][r] = 0.f;
  float mrun = -1e30f, lrun = 0.f;

  const unsigned short* kbase = kS + ((size_t)(b * 128) * 2 + g) * 4 * 512 + lane * 8;
  const unsigned short* vbase = vS + (size_t)(b * 128) * 8 * 512 + lane * 8;
  #define KFRAG(kt, ks) (kbase + ((size_t)(kt) * 8 + (ks)) * 512)
  #define VFRAG(kt, f)  (vbase + ((size_t)(kt) * 8 + (f)) * 512)

  bf16x8 kf[4];
  if (kt0 < kt1) {
    #pragma unroll
    for (int ks = 0; ks < 4; ++ks)
      kf[ks] = *reinterpret_cast<const bf16x8*>(KFRAG(kt0, ks));
  }

  for (int kt = kt0; kt < kt1; ++kt) {
    bf16x8 vfa[4], vfb[4];
    #pragma unroll
    for (int vcb = 0; vcb < 4; ++vcb) {
      vfa[vcb] = *reinterpret_cast<const bf16x8*>(VFRAG(kt, vcb * 2));
      vfb[vcb] = *reinterpret_cast<const bf16x8*>(VFRAG(kt, vcb * 2 + 1));
    }
    bf16x8 kfn[4];
    const bool more = (kt + 1 < kt1);
    if (more) {
      #pragma unroll
      for (int ks = 0; ks < 4; ++ks)
        kfn[ks] = *reinterpret_cast<const bf16x8*>(KFRAG(kt + 1, ks));
    }
    f32x16 sc;
    #pragma unroll
    for (int r = 0; r < 16; ++r) sc[r] = 0.f;
    #pragma unroll
    for (int ks = 0; ks < 4; ++ks)
      sc = __builtin_amdgcn_mfma_f32_32x32x16_bf16(kf[ks], qf[ks], sc, 0, 0, 0);

    float p[16];
    if (kt == n - 1) {
      #pragma unroll
      for (int r = 0; r < 16; ++r) {
        int rloc = (r & 3) + 8 * (r >> 2) + 4 * lh;
        p[r] = (rloc > lq) ? -1e30f : sc[r];
      }
    } else {
      #pragma unroll
      for (int r = 0; r < 16; ++r) p[r] = sc[r];
    }
    float t16[16];
    #pragma unroll
    for (int r = 0; r < 16; ++r) t16[r] = p[r];
    #pragma unroll
    for (int st = 8; st >= 1; st >>= 1)
      #pragma unroll
      for (int r = 0; r < 8; ++r)
        if (r < st) t16[r] = fmaxf(t16[r], t16[r + st]);
    float pmax = fmaxf(t16[0], __shfl_xor(t16[0], 32));
    if (__any(pmax > mrun + 8.f)) {
      float mn = fmaxf(mrun, pmax);
      float al = __expf(mrun - mn);
      lrun *= al;
      #pragma unroll
      for (int v = 0; v < 4; ++v)
        #pragma unroll
        for (int r = 0; r < 16; ++r) acc[v][r] *= al;
      mrun = mn;
    }
    float psum;
    {
      float s16[16];
      #pragma unroll
      for (int r = 0; r < 16; ++r) { p[r] = __expf(p[r] - mrun); s16[r] = p[r]; }
      #pragma unroll
      for (int st = 8; st >= 1; st >>= 1)
        #pragma unroll
        for (int r = 0; r < 8; ++r)
          if (r < st) s16[r] += s16[r + st];
      psum = s16[0];
    }
    lrun += psum + __shfl_xor(psum, 32);

    unsigned A0 = cvt_pk_bf16(p[0],  p[1]),  A1 = cvt_pk_bf16(p[2],  p[3]);
    unsigned A2 = cvt_pk_bf16(p[4],  p[5]),  A3 = cvt_pk_bf16(p[6],  p[7]);
    unsigned A4 = cvt_pk_bf16(p[8],  p[9]),  A5 = cvt_pk_bf16(p[10], p[11]);
    unsigned A6 = cvt_pk_bf16(p[12], p[13]), A7 = cvt_pk_bf16(p[14], p[15]);
    unsigned pA0 = (unsigned)__shfl_xor((int)A0, 32);
    unsigned pA1 = (unsigned)__shfl_xor((int)A1, 32);
    unsigned pA2 = (unsigned)__shfl_xor((int)A2, 32);
    unsigned pA3 = (unsigned)__shfl_xor((int)A3, 32);
    unsigned pA4 = (unsigned)__shfl_xor((int)A4, 32);
    unsigned pA5 = (unsigned)__shfl_xor((int)A5, 32);
    unsigned pA6 = (unsigned)__shfl_xor((int)A6, 32);
    unsigned pA7 = (unsigned)__shfl_xor((int)A7, 32);
    u32x4 w0, w1;
    w0[0] = lh ? pA2 : A0;  w0[1] = lh ? pA3 : A1;
    w0[2] = lh ? A2  : pA0; w0[3] = lh ? A3  : pA1;
    w1[0] = lh ? pA6 : A4;  w1[1] = lh ? pA7 : A5;
    w1[2] = lh ? A6  : pA4; w1[3] = lh ? A7  : pA5;
    bf16x8 pb0 = *reinterpret_cast<bf16x8*>(&w0);
    bf16x8 pb1 = *reinterpret_cast<bf16x8*>(&w1);
    #pragma unroll
    for (int vcb = 0; vcb < 4; ++vcb) {
      acc[vcb] = __builtin_amdgcn_mfma_f32_32x32x16_bf16(vfa[vcb], pb0, acc[vcb], 0, 0, 0);
      acc[vcb] = __builtin_amdgcn_mfma_f32_32x32x16_bf16(vfb[vcb], pb1, acc[vcb], 0, 0, 0);
    }
    if (more) {
      #pragma unroll
      for (int ks = 0; ks < 4; ++ks) kf[ks] = kfn[ks];
    }
  }
  #undef KFRAG
  #undef VFRAG
  const size_t pbase = (size_t)slot * (HD * 32);
  #pragma unroll
  for (int vcb = 0; vcb < 4; ++vcb)
    #pragma unroll
    for (int r = 0; r < 16; ++r) {
      int vc = vcb * 32 + (r & 3) + 8 * (r >> 2) + 4 * lh;
      po[pbase + (size_t)vc * 32 + lq] = f2bf(acc[vcb][r]);
    }
  if (lane < 32) {
    pm[slot * 32 + lq] = mrun;
    pl[slot * 32 + lq] = lrun;
  }
}

// ---------------- Kernel 3: merge partials (unchanged) --------------------
template<int LOG2S>
__global__ __launch_bounds__(256) void diff_merge(
    const unsigned short* __restrict__ po, const float* __restrict__ pm,
    const float* __restrict__ pl,
    const float* __restrict__ lq1, const float* __restrict__ lq2,
    const float* __restrict__ lk1, const float* __restrict__ lk2,
    const float* __restrict__ lnw, float* __restrict__ out)
{
  constexpr int S = 1 << LOG2S;
  __shared__ float red[4][32];
  const int tid = threadIdx.x, lane = tid & 63, wid = tid >> 6;
  const int q = tid & 31, vg = tid >> 5;
  const int bq = blockIdx.x;
  const int b = bq >> 7, qt = bq & 127;

  float la = lq1[lane] * lk1[lane];
  float lb = lq2[lane] * lk2[lane];
  #pragma unroll
  for (int off = 32; off >= 1; off >>= 1) {
    la += __shfl_xor(la, off);
    lb += __shfl_xor(lb, off);
  }
  const float lam = __expf(la) - __expf(lb) + LAMBDA_INIT;

  const int p1 = (bq * 2 + 0) * S;
  const int p2 = (bq * 2 + 1) * S;
  float w1[S], w2[S];
  {
    float ms[S];
    #pragma unroll
    for (int s = 0; s < S; ++s) ms[s] = pm[(p1 + s) * 32 + q];
    float M = ms[0];
    #pragma unroll
    for (int s = 1; s < S; ++s) M = fmaxf(M, ms[s]);
    float L = 0.f;
    #pragma unroll
    for (int s = 0; s < S; ++s) { w1[s] = __expf(ms[s] - M); L += w1[s] * pl[(p1 + s) * 32 + q]; }
    float inv = 1.f / L;
    #pragma unroll
    for (int s = 0; s < S; ++s) w1[s] *= inv;
  }
  {
    float ms[S];
    #pragma unroll
    for (int s = 0; s < S; ++s) ms[s] = pm[(p2 + s) * 32 + q];
    float M = ms[0];
    #pragma unroll
    for (int s = 1; s < S; ++s) M = fmaxf(M, ms[s]);
    float L = 0.f;
    #pragma unroll
    for (int s = 0; s < S; ++s) { w2[s] = __expf(ms[s] - M); L += w2[s] * pl[(p2 + s) * 32 + q]; }
    float inv = lam / L;
    #pragma unroll
    for (int s = 0; s < S; ++s) w2[s] *= inv;
  }
  float d[16], ss = 0.f;
  #pragma unroll
  for (int i = 0; i < 16; ++i) {
    int vc = vg * 16 + i;
    float a1 = 0.f, a2 = 0.f;
    #pragma unroll
    for (int s = 0; s < S; ++s) {
      a1 += w1[s] * bf2f(po[(size_t)(p1 + s) * (HD * 32) + (size_t)vc * 32 + q]);
      a2 += w2[s] * bf2f(po[(size_t)(p2 + s) * (HD * 32) + (size_t)vc * 32 + q]);
    }
    d[i] = a1 - a2;
    ss += d[i] * d[i];
  }
  ss += __shfl_xor(ss, 32);
  if (lane < 32) red[wid][q] = ss;
  __syncthreads();
  float tot = red[0][q] + red[1][q] + red[2][q] + red[3][q];
  float rinv = 1.f / sqrtf(tot * (1.0f / HD) + 1e-5f);
  float* op = out + ((size_t)b * T_SEQ + qt * 32 + q) * HD + vg * 16;
  #pragma unroll
  for (int i = 0; i < 16; ++i) op[i] = OUT_SCALE * d[i] * rinv * lnw[vg * 16 + i];
}

extern "C" void kernel_launch(void* const* d_in, const int* in_sizes, int n_in,
                              void* d_out, int out_size, void* d_ws, size_t ws_size,
                              hipStream_t stream) {
  const float* x   = (const float*)d_in[0];
  const float* wq  = (const float*)d_in[1];
  const float* wk  = (const float*)d_in[2];
  const float* wv  = (const float*)d_in[3];
  const float* lq1 = (const float*)d_in[4];
  const float* lq2 = (const float*)d_in[5];
  const float* lk1 = (const float*)d_in[6];
  const float* lk2 = (const float*)d_in[7];
  const float* lnw = (const float*)d_in[8];
  float* out = (float*)d_out;

  const size_t N = (size_t)NB * T_SEQ * HD;               // 1,048,576
  const size_t WTN = (size_t)3 * 32 * 8192;               // 786,432 ushorts
  const size_t PB  = (size_t)2 * 3 * 8192 * 128 * 4;      // 25 MB f32 partials
  int log2S = 3;
  size_t parts = 0, region = 0;
  for (;; --log2S) {
    parts = ((size_t)NB * 128 * 2) << log2S;
    size_t pob = parts * (HD * 32) * 2;
    size_t rmin = PB + WTN * 2;
    region = (pob > rmin) ? pob : rmin;
    size_t need = 3 * N * 2 + region + parts * 32 * 8;
    if (need <= ws_size || log2S == 0) break;
  }

  unsigned short* qb = (unsigned short*)d_ws;
  unsigned short* kS = qb + N;
  unsigned short* vS = kS + N;
  unsigned short* po = vS + N;                  // region of `region` bytes
  float* Ppart = (float*)po;                    // dead before attn writes po
  unsigned short* wT = (unsigned short*)((char*)po + region) - WTN;  // tail alias
  float* pm = (float*)((char*)po + region);
  float* pl = pm + parts * 32;

  wtrans<<<dim3(32, 3), 256, 0, stream>>>(wq, wk, wv, wT);
  qkv_part<<<dim3(256), 256, 0, stream>>>(x, wT, Ppart);
  qkv_merge<<<dim3(1536), 256, 0, stream>>>(Ppart, qb, kS, vS);
  const int ablocks = (int)(parts / 4);
  switch (log2S) {
    case 3:
      diff_attn_part<3><<<dim3(ablocks), 256, 0, stream>>>(qb, kS, vS, po, pm, pl);
      diff_merge<3><<<dim3(NB * 128), 256, 0, stream>>>(po, pm, pl, lq1, lq2, lk1, lk2, lnw, out);
      break;
    case 2:
      diff_attn_part<2><<<dim3(ablocks), 256, 0, stream>>>(qb, kS, vS, po, pm, pl);
      diff_merge<2><<<dim3(NB * 128), 256, 0, stream>>>(po, pm, pl, lq1, lq2, lk1, lk2, lnw, out);
      break;
    case 1:
      diff_attn_part<1><<<dim3(ablocks), 256, 0, stream>>>(qb, kS, vS, po, pm, pl);
      diff_merge<1><<<dim3(NB * 128), 256, 0, stream>>>(po, pm, pl, lq1, lq2, lk1, lk2, lnw, out);
      break;
    default:
      diff_attn_part<0><<<dim3(ablocks), 256, 0, stream>>>(qb, kS, vS, po, pm, pl);
      diff_merge<0><<<dim3(NB * 128), 256, 0, stream>>>(po, pm, pl, lq1, lq2, lk1, lk2, lnw, out);
      break;
  }
}

// Round 16
// 78.547 us; speedup vs baseline: 1.4129x; 1.0131x over previous
//
#include <hip/hip_runtime.h>
#include <stdint.h>

#define T_SEQ 4096
#define NB 2
#define D_MODEL 2048
#define HD 128

typedef __attribute__((ext_vector_type(4)))  float f32x4;
typedef __attribute__((ext_vector_type(16))) float f32x16;
typedef __attribute__((ext_vector_type(8)))  short bf16x8;
typedef __attribute__((ext_vector_type(4)))  unsigned u32x4;

#define LAMBDA_INIT 0.7836057665316244f
#define OUT_SCALE   0.21639423346837556f

__device__ __forceinline__ unsigned short f2bf(float f) {
  unsigned int u = __float_as_uint(f);
  u += 0x7FFFu + ((u >> 16) & 1u);
  return (unsigned short)(u >> 16);
}
__device__ __forceinline__ float bf2f(unsigned short h) {
  return __uint_as_float(((unsigned int)h) << 16);
}
__device__ __forceinline__ unsigned cvt_pk_bf16(float a, float b) {
  unsigned r;
  asm("v_cvt_pk_bf16_f32 %0, %1, %2" : "=v"(r) : "v"(a), "v"(b));
  return r;
}
__device__ __forceinline__ void gload16(const void* g, void* l) {
  __builtin_amdgcn_global_load_lds(
      (const __attribute__((address_space(1))) unsigned int*)g,
      (__attribute__((address_space(3))) unsigned int*)l, 16, 0, 0);
}

// ---------------- Kernel 0: pre-pack W into fragment-ordered bf16 ---------
__global__ __launch_bounds__(256) void wtrans(
    const float* __restrict__ wq, const float* __restrict__ wk,
    const float* __restrict__ wv, unsigned short* __restrict__ wT)
{
  const int which = blockIdx.y;
  const int s = blockIdx.x;                     // k-slab 0..31
  const float* w = (which == 0) ? wq : ((which == 1) ? wk : wv);
  const float scale = (which == 0) ? 0.125f : 1.0f;
  const int tid = threadIdx.x;
  #pragma unroll
  for (int j = 0; j < 4; ++j) {
    int cell = j * 256 + tid;                   // 0..1023
    int q = cell >> 7, n = cell & 127;
    int kb = s * 64 + q * 8;
    float v[8];
    #pragma unroll
    for (int e = 0; e < 8; ++e) v[e] = w[(size_t)(kb + e) * HD + n] * scale;
    u32x4 pk = { cvt_pk_bf16(v[0], v[1]), cvt_pk_bf16(v[2], v[3]),
                 cvt_pk_bf16(v[4], v[5]), cvt_pk_bf16(v[6], v[7]) };
    *reinterpret_cast<u32x4*>(&wT[(size_t)(which * 32 + s) * 8192 + (size_t)cell * 8]) = pk;
  }
}

// ---------------- Kernel 1a: fused QKV K-split partials (full-DMA) --------
// grid 256: (mt 128) x (ks 2), 512 threads (8 waves = 2/SIMD for TLP).
// Block computes q,k,v for 64 rows, K=1024 (32 steps of 32). Ring-4 LDS
// (32KB/slot), prefetch distance 3 (R15-proven). Per-wave DMA 4 instr/step
// -> counted vmcnt(8/4/0). Wave tile 16m x 64n, 12 MFMA/step.
__global__ __launch_bounds__(512, 1) void qkv_part(
    const float* __restrict__ x, const unsigned short* __restrict__ wT,
    float* __restrict__ P)
{
  __shared__ __align__(16) char lds[4][32768];   // 128 KB
  const int tid = threadIdx.x, lane = tid & 63, wid = tid >> 6;   // wid 0..7
  const int bid = blockIdx.x;
  const int ks = bid & 1;
  const int mt = bid >> 1;
  const int wm = wid >> 1, wn = wid & 1;        // wave tile 16(m) x 64(n)
  const int fr = lane & 15, fq = lane >> 4;
  const int m0 = mt * 64;

  const float* xbase = x + (size_t)m0 * D_MODEL + ks * 1024;
  const unsigned short* wbase = wT + (size_t)(ks * 16) * 8192;  // +type*262144

  f32x4 acc[3][4];
  #pragma unroll
  for (int ty = 0; ty < 3; ++ty)
    #pragma unroll
    for (int j = 0; j < 4; ++j) acc[ty][j] = (f32x4){0.f, 0.f, 0.f, 0.f};

// DMA step t into slot t&3. Per wave: 1 A + 3 B = 4 instructions.
#define DMA(t) do {                                                        \
    char* As_ = &lds[(t) & 3][0];                                          \
    char* Bs_ = &lds[(t) & 3][8192];                                       \
    const int k0_ = (t) * 32;                                              \
    {                                                                      \
      int c = wid * 64 + lane;                                             \
      int row = c >> 3, kcp = c & 7;                                       \
      gload16(xbase + (size_t)row * D_MODEL + k0_ + ((kcp ^ (row & 7)) << 2), \
              As_ + wid * 1024);                                           \
    }                                                                      \
    _Pragma("unroll")                                                      \
    for (int ty = 0; ty < 3; ++ty) {                                       \
      const unsigned short* bs_ = wbase + (size_t)ty * 262144              \
                                + (size_t)((t) >> 1) * 8192                \
                                + (size_t)((t) & 1) * 4096;                \
      gload16(bs_ + (size_t)wid * 512 + (size_t)lane * 8,                  \
              Bs_ + (size_t)ty * 8192 + wid * 1024);                       \
    }                                                                      \
  } while (0)

#define STEP(t, VMIMM) do {                                                \
    asm volatile("s_waitcnt vmcnt(" VMIMM ")" ::: "memory");               \
    __builtin_amdgcn_s_barrier();                                          \
    __builtin_amdgcn_sched_barrier(0);                                     \
    if ((t) + 3 < 32) DMA((t) + 3);                                        \
    __builtin_amdgcn_sched_barrier(0);                                     \
    const char* Ac_ = &lds[(t) & 3][0];                                    \
    const char* Bc_ = &lds[(t) & 3][8192];                                 \
    bf16x8 af_;                                                            \
    {                                                                      \
      int row = wm * 16 + fr;                                              \
      int p1 = (2 * fq) ^ (row & 7), p2 = (2 * fq + 1) ^ (row & 7);        \
      f32x4 lo = *reinterpret_cast<const f32x4*>(Ac_ + (row * 8 + p1) * 16); \
      f32x4 hi = *reinterpret_cast<const f32x4*>(Ac_ + (row * 8 + p2) * 16); \
      u32x4 pk = { cvt_pk_bf16(lo[0], lo[1]), cvt_pk_bf16(lo[2], lo[3]),   \
                   cvt_pk_bf16(hi[0], hi[1]), cvt_pk_bf16(hi[2], hi[3]) }; \
      af_ = *reinterpret_cast<bf16x8*>(&pk);                               \
    }                                                                      \
    _Pragma("unroll")                                                      \
    for (int ty = 0; ty < 3; ++ty)                                         \
      _Pragma("unroll")                                                    \
      for (int ni = 0; ni < 4; ++ni) {                                     \
        int n = wn * 64 + ni * 16 + fr;                                    \
        bf16x8 bf_ = *reinterpret_cast<const bf16x8*>(                     \
            Bc_ + (size_t)ty * 8192 + (fq * 128 + n) * 16);                \
        acc[ty][ni] = __builtin_amdgcn_mfma_f32_16x16x32_bf16(af_, bf_, acc[ty][ni], 0, 0, 0); \
      }                                                                    \
  } while (0)

  DMA(0); DMA(1); DMA(2);
  #pragma unroll 1
  for (int t = 0; t < 30; ++t) STEP(t, "8");
  STEP(30, "4");
  STEP(31, "0");
#undef STEP
#undef DMA

  // partial store: P[((ks*3+type)*8192 + m)*128 + n]
  #pragma unroll
  for (int ty = 0; ty < 3; ++ty) {
    float* pp = P + ((size_t)(ks * 3 + ty) * 8192 + m0) * 128;
    #pragma unroll
    for (int ni = 0; ni < 4; ++ni)
      #pragma unroll
      for (int r = 0; r < 4; ++r)
        pp[(size_t)(wm * 16 + fq * 4 + r) * 128 + wn * 64 + ni * 16 + fr]
            = acc[ty][ni][r];
  }
}

// ---------------- Kernel 1b: merge partials + fragment scatter ------------
__global__ __launch_bounds__(256) void qkv_merge(
    const float* __restrict__ P,
    unsigned short* __restrict__ qb, unsigned short* __restrict__ kS,
    unsigned short* __restrict__ vS)
{
  const int gid = blockIdx.x * 256 + threadIdx.x;   // 0..393215
  const size_t e8 = (size_t)gid * 8;
  const int type = (int)(e8 >> 20);                  // 8192*128 = 2^20
  const int rem  = (int)(e8 & 1048575);
  const int m = rem >> 7, n0 = rem & 127;
  const float* p0 = P + (size_t)type * 1048576 + rem;
  const float* p1 = p0 + (size_t)3 * 1048576;
  f32x4 a0 = *reinterpret_cast<const f32x4*>(p0);
  f32x4 a1 = *reinterpret_cast<const f32x4*>(p0 + 4);
  f32x4 b0 = *reinterpret_cast<const f32x4*>(p1);
  f32x4 b1 = *reinterpret_cast<const f32x4*>(p1 + 4);
  float s[8];
  #pragma unroll
  for (int j = 0; j < 4; ++j) { s[j] = a0[j] + b0[j]; s[4 + j] = a1[j] + b1[j]; }
  u32x4 pk = { cvt_pk_bf16(s[0], s[1]), cvt_pk_bf16(s[2], s[3]),
               cvt_pk_bf16(s[4], s[5]), cvt_pk_bf16(s[6], s[7]) };

  const int bb = m >> 12, tt = m & 4095;
  const int kt = tt >> 5, kvl = tt & 31;
  if (type == 0) {
    *reinterpret_cast<u32x4*>(&qb[(size_t)m * HD + n0]) = pk;
  } else if (type == 1) {
    int g = n0 >> 6, hl = n0 & 63;
    int ksf = hl >> 4, r8 = (hl >> 3) & 1;
    size_t idx = ((((((size_t)bb * 128 + kt) * 2 + g) * 4) + ksf) << 9)
               + (size_t)(kvl + 32 * r8) * 8;
    *reinterpret_cast<u32x4*>(&kS[idx]) = pk;
  } else {
    int f = kvl >> 4, r8v = (kvl >> 3) & 1, e = kvl & 7;
    #pragma unroll
    for (int j = 0; j < 8; ++j) {
      int n = n0 + j;
      int vcb = n >> 5;
      size_t idx = (((((size_t)bb * 128 + kt) * 8) + vcb * 2 + f) << 9)
                 + (size_t)((n & 31) + 32 * r8v) * 8 + e;
      vS[idx] = f2bf(s[j]);
    }
  }
}

// ---------------- Kernel 2: per-wave flash partials (unchanged) -----------
template<int LOG2S>
__global__ __launch_bounds__(256, 2) void diff_attn_part(
    const unsigned short* __restrict__ qb, const unsigned short* __restrict__ kS,
    const unsigned short* __restrict__ vS,
    unsigned short* __restrict__ po, float* __restrict__ pm, float* __restrict__ pl)
{
  constexpr int S = 1 << LOG2S;
  const int tid = threadIdx.x, lane = tid & 63, wid = tid >> 6;
  const int wave_id = blockIdx.x * 4 + wid;
  const int sp = wave_id & (S - 1);
  const int g  = (wave_id >> LOG2S) & 1;
  const int qt_raw = (wave_id >> (LOG2S + 1)) & 127;
  const int b  = wave_id >> (LOG2S + 8);
  const int qt = 127 - qt_raw;                  // heavy-first scheduling
  const int slot = (((b * 128 + qt) * 2 + g) << LOG2S) + sp;
  const int lq = lane & 31, lh = lane >> 5;
  const int q0 = qt * 32;
  const int n  = qt + 1;
  const int kt0 = (n * sp) >> LOG2S;
  const int kt1 = (n * (sp + 1)) >> LOG2S;

  bf16x8 qf[4];
  const unsigned short* qp = qb + ((size_t)b * T_SEQ + q0 + lq) * HD + g * 64 + lh * 8;
  #pragma unroll
  for (int ks = 0; ks < 4; ++ks) qf[ks] = *reinterpret_cast<const bf16x8*>(qp + ks * 16);

  f32x16 acc[4];
  #pragma unroll
  for (int v = 0; v < 4; ++v)
    #pragma unroll
    for (int r = 0; r < 16; ++r) acc[v][r] = 0.f;
  float mrun = -1e30f, lrun = 0.f;

  const unsigned short* kbase = kS + ((size_t)(b * 128) * 2 + g) * 4 * 512 + lane * 8;
  const unsigned short* vbase = vS + (size_t)(b * 128) * 8 * 512 + lane * 8;
  #define KFRAG(kt, ks) (kbase + ((size_t)(kt) * 8 + (ks)) * 512)
  #define VFRAG(kt, f)  (vbase + ((size_t)(kt) * 8 + (f)) * 512)

  bf16x8 kf[4];
  if (kt0 < kt1) {
    #pragma unroll
    for (int ks = 0; ks < 4; ++ks)
      kf[ks] = *reinterpret_cast<const bf16x8*>(KFRAG(kt0, ks));
  }

  for (int kt = kt0; kt < kt1; ++kt) {
    bf16x8 vfa[4], vfb[4];
    #pragma unroll
    for (int vcb = 0; vcb < 4; ++vcb) {
      vfa[vcb] = *reinterpret_cast<const bf16x8*>(VFRAG(kt, vcb * 2));
      vfb[vcb] = *reinterpret_cast<const bf16x8*>(VFRAG(kt, vcb * 2 + 1));
    }
    bf16x8 kfn[4];
    const bool more = (kt + 1 < kt1);
    if (more) {
      #pragma unroll
      for (int ks = 0; ks < 4; ++ks)
        kfn[ks] = *reinterpret_cast<const bf16x8*>(KFRAG(kt + 1, ks));
    }
    f32x16 sc;
    #pragma unroll
    for (int r = 0; r < 16; ++r) sc[r] = 0.f;
    #pragma unroll
    for (int ks = 0; ks < 4; ++ks)
      sc = __builtin_amdgcn_mfma_f32_32x32x16_bf16(kf[ks], qf[ks], sc, 0, 0, 0);

    float p[16];
    if (kt == n - 1) {
      #pragma unroll
      for (int r = 0; r < 16; ++r) {
        int rloc = (r & 3) + 8 * (r >> 2) + 4 * lh;
        p[r] = (rloc > lq) ? -1e30f : sc[r];
      }
    } else {
      #pragma unroll
      for (int r = 0; r < 16; ++r) p[r] = sc[r];
    }
    float t16[16];
    #pragma unroll
    for (int r = 0; r < 16; ++r) t16[r] = p[r];
    #pragma unroll
    for (int st = 8; st >= 1; st >>= 1)
      #pragma unroll
      for (int r = 0; r < 8; ++r)
        if (r < st) t16[r] = fmaxf(t16[r], t16[r + st]);
    float pmax = fmaxf(t16[0], __shfl_xor(t16[0], 32));
    if (__any(pmax > mrun + 8.f)) {
      float mn = fmaxf(mrun, pmax);
      float al = __expf(mrun - mn);
      lrun *= al;
      #pragma unroll
      for (int v = 0; v < 4; ++v)
        #pragma unroll
        for (int r = 0; r < 16; ++r) acc[v][r] *= al;
      mrun = mn;
    }
    float psum;
    {
      float s16[16];
      #pragma unroll
      for (int r = 0; r < 16; ++r) { p[r] = __expf(p[r] - mrun); s16[r] = p[r]; }
      #pragma unroll
      for (int st = 8; st >= 1; st >>= 1)
        #pragma unroll
        for (int r = 0; r < 8; ++r)
          if (r < st) s16[r] += s16[r + st];
      psum = s16[0];
    }
    lrun += psum + __shfl_xor(psum, 32);

    unsigned A0 = cvt_pk_bf16(p[0],  p[1]),  A1 = cvt_pk_bf16(p[2],  p[3]);
    unsigned A2 = cvt_pk_bf16(p[4],  p[5]),  A3 = cvt_pk_bf16(p[6],  p[7]);
    unsigned A4 = cvt_pk_bf16(p[8],  p[9]),  A5 = cvt_pk_bf16(p[10], p[11]);
    unsigned A6 = cvt_pk_bf16(p[12], p[13]), A7 = cvt_pk_bf16(p[14], p[15]);
    unsigned pA0 = (unsigned)__shfl_xor((int)A0, 32);
    unsigned pA1 = (unsigned)__shfl_xor((int)A1, 32);
    unsigned pA2 = (unsigned)__shfl_xor((int)A2, 32);
    unsigned pA3 = (unsigned)__shfl_xor((int)A3, 32);
    unsigned pA4 = (unsigned)__shfl_xor((int)A4, 32);
    unsigned pA5 = (unsigned)__shfl_xor((int)A5, 32);
    unsigned pA6 = (unsigned)__shfl_xor((int)A6, 32);
    unsigned pA7 = (unsigned)__shfl_xor((int)A7, 32);
    u32x4 w0, w1;
    w0[0] = lh ? pA2 : A0;  w0[1] = lh ? pA3 : A1;
    w0[2] = lh ? A2  : pA0; w0[3] = lh ? A3  : pA1;
    w1[0] = lh ? pA6 : A4;  w1[1] = lh ? pA7 : A5;
    w1[2] = lh ? A6  : pA4; w1[3] = lh ? A7  : pA5;
    bf16x8 pb0 = *reinterpret_cast<bf16x8*>(&w0);
    bf16x8 pb1 = *reinterpret_cast<bf16x8*>(&w1);
    #pragma unroll
    for (int vcb = 0; vcb < 4; ++vcb) {
      acc[vcb] = __builtin_amdgcn_mfma_f32_32x32x16_bf16(vfa[vcb], pb0, acc[vcb], 0, 0, 0);
      acc[vcb] = __builtin_amdgcn_mfma_f32_32x32x16_bf16(vfb[vcb], pb1, acc[vcb], 0, 0, 0);
    }
    if (more) {
      #pragma unroll
      for (int ks = 0; ks < 4; ++ks) kf[ks] = kfn[ks];
    }
  }
  #undef KFRAG
  #undef VFRAG
  const size_t pbase = (size_t)slot * (HD * 32);
  #pragma unroll
  for (int vcb = 0; vcb < 4; ++vcb)
    #pragma unroll
    for (int r = 0; r < 16; ++r) {
      int vc = vcb * 32 + (r & 3) + 8 * (r >> 2) + 4 * lh;
      po[pbase + (size_t)vc * 32 + lq] = f2bf(acc[vcb][r]);
    }
  if (lane < 32) {
    pm[slot * 32 + lq] = mrun;
    pl[slot * 32 + lq] = lrun;
  }
}

// ---------------- Kernel 3: merge partials (unchanged) --------------------
template<int LOG2S>
__global__ __launch_bounds__(256) void diff_merge(
    const unsigned short* __restrict__ po, const float* __restrict__ pm,
    const float* __restrict__ pl,
    const float* __restrict__ lq1, const float* __restrict__ lq2,
    const float* __restrict__ lk1, const float* __restrict__ lk2,
    const float* __restrict__ lnw, float* __restrict__ out)
{
  constexpr int S = 1 << LOG2S;
  __shared__ float red[4][32];
  const int tid = threadIdx.x, lane = tid & 63, wid = tid >> 6;
  const int q = tid & 31, vg = tid >> 5;
  const int bq = blockIdx.x;
  const int b = bq >> 7, qt = bq & 127;

  float la = lq1[lane] * lk1[lane];
  float lb = lq2[lane] * lk2[lane];
  #pragma unroll
  for (int off = 32; off >= 1; off >>= 1) {
    la += __shfl_xor(la, off);
    lb += __shfl_xor(lb, off);
  }
  const float lam = __expf(la) - __expf(lb) + LAMBDA_INIT;

  const int p1 = (bq * 2 + 0) * S;
  const int p2 = (bq * 2 + 1) * S;
  float w1[S], w2[S];
  {
    float ms[S];
    #pragma unroll
    for (int s = 0; s < S; ++s) ms[s] = pm[(p1 + s) * 32 + q];
    float M = ms[0];
    #pragma unroll
    for (int s = 1; s < S; ++s) M = fmaxf(M, ms[s]);
    float L = 0.f;
    #pragma unroll
    for (int s = 0; s < S; ++s) { w1[s] = __expf(ms[s] - M); L += w1[s] * pl[(p1 + s) * 32 + q]; }
    float inv = 1.f / L;
    #pragma unroll
    for (int s = 0; s < S; ++s) w1[s] *= inv;
  }
  {
    float ms[S];
    #pragma unroll
    for (int s = 0; s < S; ++s) ms[s] = pm[(p2 + s) * 32 + q];
    float M = ms[0];
    #pragma unroll
    for (int s = 1; s < S; ++s) M = fmaxf(M, ms[s]);
    float L = 0.f;
    #pragma unroll
    for (int s = 0; s < S; ++s) { w2[s] = __expf(ms[s] - M); L += w2[s] * pl[(p2 + s) * 32 + q]; }
    float inv = lam / L;
    #pragma unroll
    for (int s = 0; s < S; ++s) w2[s] *= inv;
  }
  float d[16], ss = 0.f;
  #pragma unroll
  for (int i = 0; i < 16; ++i) {
    int vc = vg * 16 + i;
    float a1 = 0.f, a2 = 0.f;
    #pragma unroll
    for (int s = 0; s < S; ++s) {
      a1 += w1[s] * bf2f(po[(size_t)(p1 + s) * (HD * 32) + (size_t)vc * 32 + q]);
      a2 += w2[s] * bf2f(po[(size_t)(p2 + s) * (HD * 32) + (size_t)vc * 32 + q]);
    }
    d[i] = a1 - a2;
    ss += d[i] * d[i];
  }
  ss += __shfl_xor(ss, 32);
  if (lane < 32) red[wid][q] = ss;
  __syncthreads();
  float tot = red[0][q] + red[1][q] + red[2][q] + red[3][q];
  float rinv = 1.f / sqrtf(tot * (1.0f / HD) + 1e-5f);
  float* op = out + ((size_t)b * T_SEQ + qt * 32 + q) * HD + vg * 16;
  #pragma unroll
  for (int i = 0; i < 16; ++i) op[i] = OUT_SCALE * d[i] * rinv * lnw[vg * 16 + i];
}

extern "C" void kernel_launch(void* const* d_in, const int* in_sizes, int n_in,
                              void* d_out, int out_size, void* d_ws, size_t ws_size,
                              hipStream_t stream) {
  const float* x   = (const float*)d_in[0];
  const float* wq  = (const float*)d_in[1];
  const float* wk  = (const float*)d_in[2];
  const float* wv  = (const float*)d_in[3];
  const float* lq1 = (const float*)d_in[4];
  const float* lq2 = (const float*)d_in[5];
  const float* lk1 = (const float*)d_in[6];
  const float* lk2 = (const float*)d_in[7];
  const float* lnw = (const float*)d_in[8];
  float* out = (float*)d_out;

  const size_t N = (size_t)NB * T_SEQ * HD;               // 1,048,576
  const size_t WTN = (size_t)3 * 32 * 8192;               // 786,432 ushorts
  const size_t PB  = (size_t)2 * 3 * 8192 * 128 * 4;      // 25 MB f32 partials
  int log2S = 3;
  size_t parts = 0, region = 0;
  for (;; --log2S) {
    parts = ((size_t)NB * 128 * 2) << log2S;
    size_t pob = parts * (HD * 32) * 2;
    size_t rmin = PB + WTN * 2;
    region = (pob > rmin) ? pob : rmin;
    size_t need = 3 * N * 2 + region + parts * 32 * 8;
    if (need <= ws_size || log2S == 0) break;
  }

  unsigned short* qb = (unsigned short*)d_ws;
  unsigned short* kS = qb + N;
  unsigned short* vS = kS + N;
  unsigned short* po = vS + N;                  // region of `region` bytes
  float* Ppart = (float*)po;                    // dead before attn writes po
  unsigned short* wT = (unsigned short*)((char*)po + region) - WTN;  // tail alias
  float* pm = (float*)((char*)po + region);
  float* pl = pm + parts * 32;

  wtrans<<<dim3(32, 3), 256, 0, stream>>>(wq, wk, wv, wT);
  qkv_part<<<dim3(256), 512, 0, stream>>>(x, wT, Ppart);
  qkv_merge<<<dim3(1536), 256, 0, stream>>>(Ppart, qb, kS, vS);
  const int ablocks = (int)(parts / 4);
  switch (log2S) {
    case 3:
      diff_attn_part<3><<<dim3(ablocks), 256, 0, stream>>>(qb, kS, vS, po, pm, pl);
      diff_merge<3><<<dim3(NB * 128), 256, 0, stream>>>(po, pm, pl, lq1, lq2, lk1, lk2, lnw, out);
      break;
    case 2:
      diff_attn_part<2><<<dim3(ablocks), 256, 0, stream>>>(qb, kS, vS, po, pm, pl);
      diff_merge<2><<<dim3(NB * 128), 256, 0, stream>>>(po, pm, pl, lq1, lq2, lk1, lk2, lnw, out);
      break;
    case 1:
      diff_attn_part<1><<<dim3(ablocks), 256, 0, stream>>>(qb, kS, vS, po, pm, pl);
      diff_merge<1><<<dim3(NB * 128), 256, 0, stream>>>(po, pm, pl, lq1, lq2, lk1, lk2, lnw, out);
      break;
    default:
      diff_attn_part<0><<<dim3(ablocks), 256, 0, stream>>>(qb, kS, vS, po, pm, pl);
      diff_merge<0><<<dim3(NB * 128), 256, 0, stream>>>(po, pm, pl, lq1, lq2, lk1, lk2, lnw, out);
      break;
  }
}